// Round 7
// baseline (448.499 us; speedup 1.0000x reference)
//
#include <hip/hip_runtime.h>

#define B_ 256
#define C_ 248
#define P_ 50
#define T_ 4
#define H_ 8
#define D_ 31
#define DH_ 124
#define PT_ 200
#define O3_ 744

typedef __attribute__((ext_vector_type(8))) short short8v;
typedef __attribute__((ext_vector_type(4))) float f32x4;

__device__ __forceinline__ float bf2f(unsigned short u) {
  union { unsigned int i; float f; } v; v.i = ((unsigned int)u) << 16; return v.f;
}
__device__ __forceinline__ unsigned short f2bf(float f) {
  union { float f; unsigned int i; } v; v.f = f;
  unsigned int r = v.i + 0x7fffu + ((v.i >> 16) & 1u);
  return (unsigned short)(r >> 16);
}

// K0: rel_emb fp32 -> bf16, zero-padded to [112][128]
__global__ void relcvt_kernel(const float* __restrict__ rel, unsigned short* __restrict__ out) {
  int i = blockIdx.x * 256 + threadIdx.x;
  if (i < 112 * 128) {
    int r = i >> 7, k = i & 127;
    out[i] = (r < 99 && k < DH_) ? f2bf(rel[r * DH_ + k]) : (unsigned short)0;
  }
}

// K0b: w_qkv fp32 [744][248] -> bf16 zero-padded [768][256]
__global__ void wcvt_kernel(const float* __restrict__ w, unsigned short* __restrict__ wbf) {
  int i = blockIdx.x * 256 + threadIdx.x;  // 768*64 ushort4 slots
  if (i < 768 * 64) {
    int o = i >> 6, c = (i & 63) * 4;
    ushort4 val = make_ushort4(0, 0, 0, 0);
    if (o < O3_ && c < C_) {
      float4 wv = *(const float4*)(w + (size_t)o * C_ + c);
      val.x = f2bf(wv.x); val.y = f2bf(wv.y); val.z = f2bf(wv.z); val.w = f2bf(wv.w);
    }
    *(ushort4*)(wbf + (size_t)o * 256 + c) = val;
  }
}

// K0c: x fp32 [b][248][200] -> xT bf16 [b][208][256] (pt-major, zero-padded)
__global__ __launch_bounds__(256) void xt_kernel(const float* __restrict__ x,
                                                 unsigned short* __restrict__ xT) {
  __shared__ float xs[64 * 65];
  const int tid = threadIdx.x;
  const int pt0 = (blockIdx.x & 3) * 64;
  const int c0 = (blockIdx.x >> 2) * 64;
  const int b = blockIdx.y;
#pragma unroll
  for (int pass = 0; pass < 4; ++pass) {
    int row = pass * 16 + (tid >> 4);       // c local
    int ptl4 = (tid & 15) * 4;              // pt local
    int c = c0 + row, pt = pt0 + ptl4;
    float4 v = make_float4(0.f, 0.f, 0.f, 0.f);
    if (c < C_) {
      const float* src = x + ((size_t)b * C_ + c) * PT_ + pt;
      if (pt + 3 < PT_) v = *(const float4*)src;
      else {
        if (pt + 0 < PT_) v.x = src[0];
        if (pt + 1 < PT_) v.y = src[1];
        if (pt + 2 < PT_) v.z = src[2];
        if (pt + 3 < PT_) v.w = src[3];
      }
    }
    xs[row * 65 + ptl4 + 0] = v.x; xs[row * 65 + ptl4 + 1] = v.y;
    xs[row * 65 + ptl4 + 2] = v.z; xs[row * 65 + ptl4 + 3] = v.w;
  }
  __syncthreads();
#pragma unroll
  for (int pass = 0; pass < 4; ++pass) {
    int ptl = pass * 16 + (tid >> 4);
    int cl4 = (tid & 15) * 4;
    int pt = pt0 + ptl;
    if (pt < 208) {
      ushort4 pk;
      pk.x = f2bf(xs[(cl4 + 0) * 65 + ptl]);
      pk.y = f2bf(xs[(cl4 + 1) * 65 + ptl]);
      pk.z = f2bf(xs[(cl4 + 2) * 65 + ptl]);
      pk.w = f2bf(xs[(cl4 + 3) * 65 + ptl]);
      *(ushort4*)(xT + ((size_t)b * 208 + pt) * 256 + c0 + cl4) = pk;
    }
  }
}

// K1: MFMA qkv GEMM, XCD-swizzled. 3072 blocks: xcd=wgid&7, b=xcd*32+slot/12,
// sub=slot%12 -> (otile 0..5, mhalf 0..1). 7 m-tiles/block (halves overlap tile 6:
// duplicate identical stores, benign). acc=56 VGPR -> higher occupancy.
__global__ __launch_bounds__(256) void qkv_mfma_kernel(
    const unsigned short* __restrict__ xT, const unsigned short* __restrict__ wbf,
    const float* __restrict__ bias,
    unsigned short* __restrict__ q_ws, unsigned short* __restrict__ k_ws,
    unsigned short* __restrict__ v_ws) {
  const int tid = threadIdx.x;
  const int w = tid >> 6, l = tid & 63;
  const int lr = l & 15, lk = (l >> 4) * 8;
  const int wgid = blockIdx.x;
  const int xcd = wgid & 7, slot = wgid >> 3;
  const int b = xcd * 32 + slot / 12;
  const int sub = slot - (slot / 12) * 12;
  const int otile = sub >> 1, mhalf = sub & 1;
  const int o_w = otile * 128 + w * 32;
  const int g0 = mhalf * 6;                 // first m-tile (0 or 6)
  const unsigned short* xb = xT + (size_t)b * 208 * 256;

  const f32x4 zf = {0.f, 0.f, 0.f, 0.f};
  f32x4 acc0[7], acc1[7];
#pragma unroll
  for (int m = 0; m < 7; ++m) { acc0[m] = zf; acc1[m] = zf; }

#pragma unroll
  for (int ks = 0; ks < 8; ++ks) {
    int k0 = ks * 32 + lk;
    short8v b0 = *(const short8v*)(wbf + (size_t)(o_w + lr) * 256 + k0);
    short8v b1 = *(const short8v*)(wbf + (size_t)(o_w + 16 + lr) * 256 + k0);
#pragma unroll
    for (int m = 0; m < 7; ++m) {
      short8v a = *(const short8v*)(xb + (size_t)((g0 + m) * 16 + lr) * 256 + k0);
      acc0[m] = __builtin_amdgcn_mfma_f32_16x16x32_bf16(a, b0, acc0[m], 0, 0, 0);
      acc1[m] = __builtin_amdgcn_mfma_f32_16x16x32_bf16(a, b1, acc1[m], 0, 0, 0);
    }
  }
#pragma unroll
  for (int n = 0; n < 2; ++n) {
    int o = o_w + n * 16 + lr;
    if (o < O3_) {
      float bo = bias[o];
      int wi = o / C_;
      int rem = o - wi * C_;
      int h = rem / D_;
      int d = rem - h * D_;
      unsigned short* dst = (wi == 0) ? q_ws : (wi == 1) ? k_ws : v_ws;
      size_t rowb = ((size_t)b * H_ + h) * P_;
#pragma unroll
      for (int m = 0; m < 7; ++m) {
        int p = 4 * (g0 + m) + (l >> 4);
        if (p < P_) {
          f32x4 av = (n == 0) ? acc0[m] : acc1[m];
          ushort4 pk;
          pk.x = f2bf(av[0] + bo); pk.y = f2bf(av[1] + bo);
          pk.z = f2bf(av[2] + bo); pk.w = f2bf(av[3] + bo);
          *(ushort4*)(dst + (rowb + p) * DH_ + d * T_) = pk;
        }
      }
    }
  }
}

// K2: per-(b,h) MFMA attention: (QK^T + rel bias) softmax PV + residual -> pre1
__global__ __launch_bounds__(256) void attn_kernel(
    const unsigned short* __restrict__ q_ws, const unsigned short* __restrict__ k_ws,
    const unsigned short* __restrict__ v_ws, const unsigned short* __restrict__ relp,
    const float* __restrict__ x, float* __restrict__ pre1) {
  __shared__ __align__(16) unsigned short Qs[64 * 128];
  __shared__ __align__(16) unsigned short Ks[64 * 128];
  __shared__ __align__(16) unsigned short Vt[128 * 64];
  __shared__ __align__(16) unsigned short Ps[64 * 64];
  __shared__ __align__(16) unsigned short brs[64 * 112];
  const int tid = threadIdx.x;
  const int bh = blockIdx.x, b = bh >> 3, h = bh & 7;
  const size_t off = (size_t)bh * (P_ * DH_);

  {
    float4 z = make_float4(0.f, 0.f, 0.f, 0.f);
    float4* z1 = (float4*)Qs; float4* z2 = (float4*)Ks; float4* z3 = (float4*)Vt;
    for (int i = tid; i < 1024; i += 256) { z1[i] = z; z2[i] = z; z3[i] = z; }
  }
  __syncthreads();
  const float scale = 0.17960530202677491f;
  for (int i = tid; i < 1550; i += 256) {
    int p = i / 31, kq = (i - p * 31) * 4;
    ushort4 qv = *(const ushort4*)(q_ws + off + p * DH_ + kq);
    qv.x = f2bf(bf2f(qv.x) * scale); qv.y = f2bf(bf2f(qv.y) * scale);
    qv.z = f2bf(bf2f(qv.z) * scale); qv.w = f2bf(bf2f(qv.w) * scale);
    *(ushort4*)((char*)Qs + ((p * 256 + kq * 2) ^ ((p & 7) << 4))) = qv;
    ushort4 kv = *(const ushort4*)(k_ws + off + p * DH_ + kq);
    *(ushort4*)((char*)Ks + ((p * 256 + kq * 2) ^ ((p & 7) << 4))) = kv;
    ushort4 vv = *(const ushort4*)(v_ws + off + p * DH_ + kq);
    unsigned short ve[4] = {vv.x, vv.y, vv.z, vv.w};
#pragma unroll
    for (int e = 0; e < 4; ++e) {
      int dh = kq + e;
      *(unsigned short*)((char*)Vt + ((dh * 128 + p * 2) ^ ((dh & 7) << 4))) = ve[e];
    }
  }
  __syncthreads();

  const int w = tid >> 6, l = tid & 63;
  const int lr = l & 15;
  const int lk = (l >> 4) * 8;
  const int arow = 16 * w + lr;
  const int prow0 = 16 * w + (l >> 4) * 4;

  const f32x4 zf = {0.f, 0.f, 0.f, 0.f};
  f32x4 accS[4]; f32x4 accR[7];
#pragma unroll
  for (int n = 0; n < 4; ++n) accS[n] = zf;
#pragma unroll
  for (int n = 0; n < 7; ++n) accR[n] = zf;

#pragma unroll
  for (int ks = 0; ks < 4; ++ks) {
    int k0 = ks * 32 + lk;
    short8v a = *(const short8v*)((const char*)Qs + ((arow * 256 + 2 * k0) ^ ((arow & 7) << 4)));
#pragma unroll
    for (int n = 0; n < 4; ++n) {
      int brow = 16 * n + lr;
      short8v bb = *(const short8v*)((const char*)Ks + ((brow * 256 + 2 * k0) ^ ((brow & 7) << 4)));
      accS[n] = __builtin_amdgcn_mfma_f32_16x16x32_bf16(a, bb, accS[n], 0, 0, 0);
    }
#pragma unroll
    for (int n = 0; n < 7; ++n) {
      int rrow = 16 * n + lr;
      short8v bb = *(const short8v*)(relp + rrow * 128 + k0);
      accR[n] = __builtin_amdgcn_mfma_f32_16x16x32_bf16(a, bb, accR[n], 0, 0, 0);
    }
  }
#pragma unroll
  for (int n = 0; n < 7; ++n)
#pragma unroll
    for (int r = 0; r < 4; ++r)
      brs[(prow0 + r) * 112 + 16 * n + lr] = f2bf(accR[n][r]);
  __syncthreads();

  float sv[4][4];
#pragma unroll
  for (int n = 0; n < 4; ++n)
#pragma unroll
    for (int r = 0; r < 4; ++r) {
      int p = prow0 + r, j = 16 * n + lr;
      if (p < P_ && j < P_)
        sv[n][r] = accS[n][r] + bf2f(brs[p * 112 + (49 + j - p)]);
      else
        sv[n][r] = -1e30f;
    }
#pragma unroll
  for (int r = 0; r < 4; ++r) {
    float mm = fmaxf(fmaxf(sv[0][r], sv[1][r]), fmaxf(sv[2][r], sv[3][r]));
    mm = fmaxf(mm, __shfl_xor(mm, 1));
    mm = fmaxf(mm, __shfl_xor(mm, 2));
    mm = fmaxf(mm, __shfl_xor(mm, 4));
    mm = fmaxf(mm, __shfl_xor(mm, 8));
    float ss = 0.f;
#pragma unroll
    for (int n = 0; n < 4; ++n) { float e = __expf(sv[n][r] - mm); sv[n][r] = e; ss += e; }
    ss += __shfl_xor(ss, 1); ss += __shfl_xor(ss, 2);
    ss += __shfl_xor(ss, 4); ss += __shfl_xor(ss, 8);
    float inv = 1.f / ss;
#pragma unroll
    for (int n = 0; n < 4; ++n) sv[n][r] *= inv;
  }
#pragma unroll
  for (int n = 0; n < 4; ++n)
#pragma unroll
    for (int r = 0; r < 4; ++r) {
      int p = prow0 + r, j = 16 * n + lr;
      *(unsigned short*)((char*)Ps + ((p * 128 + 2 * j) ^ ((p & 7) << 4))) = f2bf(sv[n][r]);
    }
  __syncthreads();

  f32x4 accO[8];
#pragma unroll
  for (int n = 0; n < 8; ++n) accO[n] = zf;
#pragma unroll
  for (int ks = 0; ks < 2; ++ks) {
    int j0 = ks * 32 + lk;
    short8v a = *(const short8v*)((const char*)Ps + ((arow * 128 + 2 * j0) ^ ((arow & 7) << 4)));
#pragma unroll
    for (int n = 0; n < 8; ++n) {
      int vrow = 16 * n + lr;
      short8v bb = *(const short8v*)((const char*)Vt + ((vrow * 128 + 2 * j0) ^ ((vrow & 7) << 4)));
      accO[n] = __builtin_amdgcn_mfma_f32_16x16x32_bf16(a, bb, accO[n], 0, 0, 0);
    }
  }
#pragma unroll
  for (int n = 0; n < 8; ++n) {
    int dh = 16 * n + lr;
    if (dh < DH_) {
      int c = h * D_ + (dh >> 2), t = dh & 3;
#pragma unroll
      for (int r = 0; r < 4; ++r) {
        int p = prow0 + r;
        if (p < P_) {
          size_t idx = (((size_t)b * C_ + c) * P_ + p) * T_ + t;
          pre1[idx] = accO[n][r] + x[idx];
        }
      }
    }
  }
}

// BN batch-stat reduction: per channel over (B, PT). 256 threads = one b each.
__global__ __launch_bounds__(256) void bnstat_kernel(
    const float* __restrict__ t, const float* __restrict__ g, const float* __restrict__ be,
    float* __restrict__ a, float* __restrict__ bs, int nch) {
  const int c = blockIdx.x;
  const int tid = threadIdx.x;
  const float* base = t + ((size_t)tid * nch + c) * PT_;
  float s = 0.f, s2 = 0.f;
  for (int i = 0; i < PT_; i += 4) {
    float4 v = *(const float4*)(base + i);
    s += v.x + v.y + v.z + v.w;
    s2 += v.x*v.x + v.y*v.y + v.z*v.z + v.w*v.w;
  }
#pragma unroll
  for (int off = 32; off > 0; off >>= 1) {
    s += __shfl_down(s, off);
    s2 += __shfl_down(s2, off);
  }
  __shared__ float r1[4], r2[4];
  if ((tid & 63) == 0) { r1[tid>>6] = s; r2[tid>>6] = s2; }
  __syncthreads();
  if (tid == 0) {
    s = r1[0]+r1[1]+r1[2]+r1[3];
    s2 = r2[0]+r2[1]+r2[2]+r2[3];
    const float inv = 1.f / (float)(B_ * PT_);
    float m = s * inv;
    float var = s2 * inv - m * m;
    float ai = g[c] * rsqrtf(var + 1e-5f);
    a[c] = ai;
    bs[c] = be[c] - m * ai;
  }
}

// K4a: pre1 f32 [b][248][200] -> p1T bf16 [b*50+p][1024] (K = c*4+t', col992=1.0, rest 0)
__global__ __launch_bounds__(256) void p1t_kernel(const float* __restrict__ pre1,
                                                  unsigned short* __restrict__ p1T) {
  __shared__ float xs[64][205];
  const int b = blockIdx.x;
  const int tid = threadIdx.x;
  for (int c0 = 0; c0 < C_; c0 += 64) {
    int R = (C_ - c0 < 64) ? (C_ - c0) : 64;
    __syncthreads();
    for (int e = tid; e < R * 50; e += 256) {
      int row = e / 50, pq = e - (e / 50) * 50;
      float4 v = *(const float4*)(pre1 + ((size_t)b * C_ + c0 + row) * PT_ + pq * 4);
      xs[row][pq*4+0]=v.x; xs[row][pq*4+1]=v.y; xs[row][pq*4+2]=v.z; xs[row][pq*4+3]=v.w;
    }
    __syncthreads();
    for (int u = tid; u < 50 * R; u += 256) {
      int p = u / R, cl = u - (u / R) * R;
      ushort4 pk;
      pk.x = f2bf(xs[cl][p*4+0]); pk.y = f2bf(xs[cl][p*4+1]);
      pk.z = f2bf(xs[cl][p*4+2]); pk.w = f2bf(xs[cl][p*4+3]);
      *(ushort4*)(p1T + ((size_t)b*50 + p) * 1024 + (c0+cl)*4) = pk;
    }
  }
  for (int u = tid; u < 50 * 8; u += 256) {
    int p = u >> 3, g = u & 7;
    ushort4 val = make_ushort4(0,0,0,0);
    if (g == 0) val.x = 0x3F80;  // 1.0 bf16 const column
    *(ushort4*)(p1T + ((size_t)b*50 + p) * 1024 + 992 + g*4) = val;
  }
}

// K4b: build Wbig bf16 [64 n=(f,t)][1024 K=(c,t')+const] folding conv taps, a1, b1, bc
__global__ __launch_bounds__(256) void wcfe_kernel(
    const float* __restrict__ w1, const float* __restrict__ bc1,
    const float* __restrict__ w2, const float* __restrict__ bc2,
    const float* __restrict__ a1, const float* __restrict__ b1,
    unsigned short* __restrict__ Wbig) {
  const int n = blockIdx.x;       // 0..63
  const int f = n >> 2, t = n & 3;
  const int tid = threadIdx.x;
  __shared__ float red[256];
  float partial = 0.f;
  if (tid < C_) {
    int c = tid;
    float tv[4];
    float tsum = 0.f;
#pragma unroll
    for (int tp = 0; tp < 4; ++tp) {
      int dt = tp - t;
      float v = 0.f;
      if (f < 8) { if (dt >= -1 && dt <= 1) v = w1[(f * C_ + c) * 3 + dt + 1]; }
      else       { if (dt >= -2 && dt <= 2) v = w2[((f - 8) * C_ + c) * 5 + dt + 2]; }
      tv[tp] = v; tsum += v;
    }
    float ac = a1[c];
#pragma unroll
    for (int tp = 0; tp < 4; ++tp)
      Wbig[n * 1024 + c * 4 + tp] = f2bf(ac * tv[tp]);
    partial = b1[c] * tsum;
  } else {
#pragma unroll
    for (int tp = 0; tp < 4; ++tp) {
      int col = tid * 4 + tp;
      if (col > 992 && col < 1024) Wbig[n * 1024 + col] = 0;
    }
  }
  red[tid] = partial;
  __syncthreads();
  for (int s = 128; s > 0; s >>= 1) {
    if (tid < s) red[tid] += red[tid + s];
    __syncthreads();
  }
  if (tid == 0) {
    float bias = (f < 8) ? bc1[f] : bc2[f - 8];
    Wbig[n * 1024 + 992] = f2bf(bias + red[0]);
  }
}

// K4c: MFMA GEMM: y16[m=(b,p), n=(f,t)] = p1T[m] . Wbig[n].  M=12800, N=64, K=1024.
__global__ __launch_bounds__(256) void cfe12g_kernel(
    const unsigned short* __restrict__ p1T, const unsigned short* __restrict__ Wbig,
    float* __restrict__ y16) {
  const int tid = threadIdx.x;
  const int w = tid >> 6, l = tid & 63;
  const int lr = l & 15, lk = (l >> 4) * 8;
  const int m0 = blockIdx.x * 32;
  const f32x4 zf = {0.f, 0.f, 0.f, 0.f};
  f32x4 acc0 = zf, acc1 = zf;
  const unsigned short* wrow = Wbig + (size_t)(w * 16 + lr) * 1024;
#pragma unroll
  for (int ks = 0; ks < 32; ++ks) {
    int k0 = ks * 32 + lk;
    short8v bfr = *(const short8v*)(wrow + k0);
    short8v a0 = *(const short8v*)(p1T + (size_t)(m0 + lr) * 1024 + k0);
    short8v a1v = *(const short8v*)(p1T + (size_t)(m0 + 16 + lr) * 1024 + k0);
    acc0 = __builtin_amdgcn_mfma_f32_16x16x32_bf16(a0, bfr, acc0, 0, 0, 0);
    acc1 = __builtin_amdgcn_mfma_f32_16x16x32_bf16(a1v, bfr, acc1, 0, 0, 0);
  }
  const int n = w * 16 + lr, f = n >> 2, tt = n & 3;
#pragma unroll
  for (int mt = 0; mt < 2; ++mt) {
    f32x4 av = (mt == 0) ? acc0 : acc1;
#pragma unroll
    for (int r = 0; r < 4; ++r) {
      int m = m0 + mt * 16 + (l >> 4) * 4 + r;
      int b = m / 50, p = m - (m / 50) * 50;
      y16[((size_t)b * 16 + f) * PT_ + p * 4 + tt] = av[r];
    }
  }
}

// K6: ELU(BN_cfe(y16)) -> conv3 (16->248) + BN1-residual -> pre2
__global__ __launch_bounds__(256) void cfe3_kernel(
    const float* __restrict__ y16, const float* __restrict__ ac, const float* __restrict__ bcf,
    const float* __restrict__ w3, const float* __restrict__ bc3,
    const float* __restrict__ pre1, const float* __restrict__ a1, const float* __restrict__ b1,
    float* __restrict__ pre2) {
  const int b = blockIdx.x;
  const int tid = threadIdx.x;
  __shared__ float zs[16][PT_];
  __shared__ float w3s[C_][16];
  for (int i = tid; i < C_*16; i += 256) w3s[i >> 4][i & 15] = w3[i];
  for (int e = tid; e < 16*PT_; e += 256) {
    int f = e / PT_, pt = e - f * PT_;
    float v = y16[((size_t)b*16 + f) * PT_ + pt] * ac[f] + bcf[f];
    zs[f][pt] = (v > 0.f) ? v : (__expf(v) - 1.f);
  }
  __syncthreads();
  for (int e = tid; e < C_ * P_; e += 256) {
    int c = e / P_, p = e - (e / P_) * P_;
    float b3 = bc3[c];
    float4 o = make_float4(b3, b3, b3, b3);
#pragma unroll
    for (int f = 0; f < 16; ++f) {
      float wv = w3s[c][f];
      float4 z = *(const float4*)&zs[f][p*4];
      o.x += wv * z.x; o.y += wv * z.y; o.z += wv * z.z; o.w += wv * z.w;
    }
    size_t idx = (((size_t)b * C_ + c) * P_ + p) * T_;
    float4 xr = *(const float4*)(pre1 + idx);
    float a1c = a1[c], b1c = b1[c];
    o.x += xr.x * a1c + b1c;
    o.y += xr.y * a1c + b1c;
    o.z += xr.z * a1c + b1c;
    o.w += xr.w * a1c + b1c;
    *(float4*)(pre2 + idx) = o;
  }
}

// K8: apply BN2 -> out
__global__ __launch_bounds__(256) void bnapply_kernel(
    const float* __restrict__ pre2, const float* __restrict__ a, const float* __restrict__ bs,
    float* __restrict__ out) {
  int i = blockIdx.x * 256 + threadIdx.x;
  if (i < (B_*C_*PT_)/4) {
    int row = (i * 4) / PT_;
    int c = row % C_;
    float4 v = *(const float4*)(pre2 + (size_t)i * 4);
    float ai = a[c], bi = bs[c];
    float4 o = make_float4(v.x*ai+bi, v.y*ai+bi, v.z*ai+bi, v.w*ai+bi);
    *(float4*)(out + (size_t)i * 4) = o;
  }
}

extern "C" void kernel_launch(void* const* d_in, const int* in_sizes, int n_in,
                              void* d_out, int out_size, void* d_ws, size_t ws_size,
                              hipStream_t stream) {
  const float* x        = (const float*)d_in[0];
  const float* w_qkv    = (const float*)d_in[1];
  const float* b_qkv    = (const float*)d_in[2];
  const float* rel      = (const float*)d_in[3];
  const float* g1       = (const float*)d_in[4];
  const float* beta1    = (const float*)d_in[5];
  const float* w_c1     = (const float*)d_in[6];
  const float* bc1      = (const float*)d_in[7];
  const float* w_c2     = (const float*)d_in[8];
  const float* bc2      = (const float*)d_in[9];
  const float* g_cfe    = (const float*)d_in[10];
  const float* beta_cfe = (const float*)d_in[11];
  const float* w_c3     = (const float*)d_in[12];
  const float* bc3      = (const float*)d_in[13];
  const float* g2       = (const float*)d_in[14];
  const float* beta2    = (const float*)d_in[15];
  float* out = (float*)d_out;
  char* ws = (char*)d_ws;

  // ws layout (bytes):
  //   0          q_ws bf16 (25,395,200)   [p1T bf16 26,214,400 aliases q+k after attn;
  //                                        pre2 f32 aliases after cfe12g]
  //   25395200   k_ws bf16
  //   50790400   v_ws bf16
  //   76185600   pre1 f32 (50,790,400)    [xT bf16 + wbf alias here pre-attn]
  //   126976000  y16  f32 (3,276,800)
  //   130252800  relp bf16 [112][128] (28,672)
  //   130281472  Wbig bf16 [64][1024] (131,072)
  //   130412544  stats f32
  unsigned short* q_ws  = (unsigned short*)(ws);
  unsigned short* k_ws  = (unsigned short*)(ws + 25395200);
  unsigned short* v_ws  = (unsigned short*)(ws + 50790400);
  float* pre1           = (float*)(ws + 76185600);
  unsigned short* xT    = (unsigned short*)(ws + 76185600);
  unsigned short* wbf   = (unsigned short*)(ws + 76185600 + 27262976);
  float* y16            = (float*)(ws + 126976000);
  unsigned short* relp  = (unsigned short*)(ws + 130252800);
  unsigned short* Wbig  = (unsigned short*)(ws + 130281472);
  float* st             = (float*)(ws + 130412544);
  float* a1 = st, *b1 = st + 256, *acf = st + 512, *bcf = st + 544, *a2 = st + 576, *b2 = st + 832;
  unsigned short* p1T   = (unsigned short*)ws;   // alias q+k region (dead after attn)
  float* pre2           = (float*)ws;            // alias (written by cfe3, after p1T dead)

  relcvt_kernel<<<56, 256, 0, stream>>>(rel, relp);
  wcvt_kernel<<<192, 256, 0, stream>>>(w_qkv, wbf);
  xt_kernel<<<dim3(16, 256), 256, 0, stream>>>(x, xT);
  qkv_mfma_kernel<<<3072, 256, 0, stream>>>(xT, wbf, b_qkv, q_ws, k_ws, v_ws);
  attn_kernel<<<2048, 256, 0, stream>>>(q_ws, k_ws, v_ws, relp, x, pre1);
  bnstat_kernel<<<248, 256, 0, stream>>>(pre1, g1, beta1, a1, b1, C_);
  p1t_kernel<<<256, 256, 0, stream>>>(pre1, p1T);
  wcfe_kernel<<<64, 256, 0, stream>>>(w_c1, bc1, w_c2, bc2, a1, b1, Wbig);
  cfe12g_kernel<<<400, 256, 0, stream>>>(p1T, Wbig, y16);
  bnstat_kernel<<<16, 256, 0, stream>>>(y16, g_cfe, beta_cfe, acf, bcf, 16);
  cfe3_kernel<<<256, 256, 0, stream>>>(y16, acf, bcf, w_c3, bc3, pre1, a1, b1, pre2);
  bnstat_kernel<<<248, 256, 0, stream>>>(pre2, g2, beta2, a2, b2, C_);
  bnapply_kernel<<<12400, 256, 0, stream>>>(pre2, a2, b2, out);
}

// Round 9
// 398.761 us; speedup vs baseline: 1.1247x; 1.1247x over previous
//
#include <hip/hip_runtime.h>

#define B_ 256
#define C_ 248
#define P_ 50
#define T_ 4
#define H_ 8
#define D_ 31
#define DH_ 124
#define PT_ 200
#define O3_ 744

typedef __attribute__((ext_vector_type(8))) short short8v;
typedef __attribute__((ext_vector_type(4))) float f32x4;

__device__ __forceinline__ float bf2f(unsigned short u) {
  union { unsigned int i; float f; } v; v.i = ((unsigned int)u) << 16; return v.f;
}
__device__ __forceinline__ unsigned short f2bf(float f) {
  union { float f; unsigned int i; } v; v.f = f;
  unsigned int r = v.i + 0x7fffu + ((v.i >> 16) & 1u);
  return (unsigned short)(r >> 16);
}

// K0: rel_emb fp32 -> bf16, zero-padded to [112][128]
__global__ void relcvt_kernel(const float* __restrict__ rel, unsigned short* __restrict__ out) {
  int i = blockIdx.x * 256 + threadIdx.x;
  if (i < 112 * 128) {
    int r = i >> 7, k = i & 127;
    out[i] = (r < 99 && k < DH_) ? f2bf(rel[r * DH_ + k]) : (unsigned short)0;
  }
}

// K0b: w_qkv fp32 [744][248] -> bf16 zero-padded [768][256]
__global__ void wcvt_kernel(const float* __restrict__ w, unsigned short* __restrict__ wbf) {
  int i = blockIdx.x * 256 + threadIdx.x;
  if (i < 768 * 64) {
    int o = i >> 6, c = (i & 63) * 4;
    ushort4 val = make_ushort4(0, 0, 0, 0);
    if (o < O3_ && c < C_) {
      float4 wv = *(const float4*)(w + (size_t)o * C_ + c);
      val.x = f2bf(wv.x); val.y = f2bf(wv.y); val.z = f2bf(wv.z); val.w = f2bf(wv.w);
    }
    *(ushort4*)(wbf + (size_t)o * 256 + c) = val;
  }
}

// K0c: x fp32 [b][248][200] -> xT bf16 [b][208][256] (pt-major, zero-padded)
__global__ __launch_bounds__(256) void xt_kernel(const float* __restrict__ x,
                                                 unsigned short* __restrict__ xT) {
  __shared__ float xs[64 * 65];
  const int tid = threadIdx.x;
  const int pt0 = (blockIdx.x & 3) * 64;
  const int c0 = (blockIdx.x >> 2) * 64;
  const int b = blockIdx.y;
#pragma unroll
  for (int pass = 0; pass < 4; ++pass) {
    int row = pass * 16 + (tid >> 4);
    int ptl4 = (tid & 15) * 4;
    int c = c0 + row, pt = pt0 + ptl4;
    float4 v = make_float4(0.f, 0.f, 0.f, 0.f);
    if (c < C_) {
      const float* src = x + ((size_t)b * C_ + c) * PT_ + pt;
      if (pt + 3 < PT_) v = *(const float4*)src;
      else {
        if (pt + 0 < PT_) v.x = src[0];
        if (pt + 1 < PT_) v.y = src[1];
        if (pt + 2 < PT_) v.z = src[2];
        if (pt + 3 < PT_) v.w = src[3];
      }
    }
    xs[row * 65 + ptl4 + 0] = v.x; xs[row * 65 + ptl4 + 1] = v.y;
    xs[row * 65 + ptl4 + 2] = v.z; xs[row * 65 + ptl4 + 3] = v.w;
  }
  __syncthreads();
#pragma unroll
  for (int pass = 0; pass < 4; ++pass) {
    int ptl = pass * 16 + (tid >> 4);
    int cl4 = (tid & 15) * 4;
    int pt = pt0 + ptl;
    if (pt < 208) {
      ushort4 pk;
      pk.x = f2bf(xs[(cl4 + 0) * 65 + ptl]);
      pk.y = f2bf(xs[(cl4 + 1) * 65 + ptl]);
      pk.z = f2bf(xs[(cl4 + 2) * 65 + ptl]);
      pk.w = f2bf(xs[(cl4 + 3) * 65 + ptl]);
      *(ushort4*)(xT + ((size_t)b * 208 + pt) * 256 + c0 + cl4) = pk;
    }
  }
}

// K1: FUSED qkv-GEMM + attention per (b,h). XCD-swizzled: all 8 h of a b on one XCD.
// GEMM: M=13x16 (pt from xT), N=6x16 (this head's q/k/v cols), K=256; epilogue writes
// D-frags straight into swizzled Qs (x scale), Ks, Vt (transposed) in LDS.
// Then the proven attention phase: (QK^T + rel bias) softmax PV + residual -> pre1.
__global__ __launch_bounds__(256) void fused_qa_kernel(
    const unsigned short* __restrict__ xT, const unsigned short* __restrict__ wbf,
    const float* __restrict__ bias, const unsigned short* __restrict__ relp,
    const float* __restrict__ x, float* __restrict__ pre1) {
  __shared__ __align__(16) unsigned short Qs[64 * 128];
  __shared__ __align__(16) unsigned short Ks[64 * 128];
  __shared__ __align__(16) unsigned short Vt[128 * 64];
  __shared__ __align__(16) unsigned short Ps[64 * 64];
  __shared__ __align__(16) unsigned short brs[64 * 112];
  const int tid = threadIdx.x;
  const int xcd = blockIdx.x & 7, slot = blockIdx.x >> 3;
  const int b = xcd * 32 + (slot >> 3), h = slot & 7;
  const unsigned short* xb = xT + (size_t)b * 208 * 256;
  const int w = tid >> 6, l = tid & 63;
  const int lr = l & 15, lk = (l >> 4) * 8;
  const int mstart = (w == 0) ? 0 : (1 + 3 * w);   // {0,4,7,10}
  const int mcount = (w == 0) ? 4 : 3;
  const float scale = 0.17960530202677491f;

  // zero Qs/Ks/Vt (padding regions must be 0; valid entries overwritten below)
  {
    float4 z = make_float4(0.f, 0.f, 0.f, 0.f);
    float4* z1 = (float4*)Qs; float4* z2 = (float4*)Ks; float4* z3 = (float4*)Vt;
    for (int i = tid; i < 1024; i += 256) { z1[i] = z; z2[i] = z; z3[i] = z; }
  }

  // ---- GEMM phase (global reads only) ----
  const f32x4 zf = {0.f, 0.f, 0.f, 0.f};
  f32x4 acc[4][6];
#pragma unroll
  for (int mi = 0; mi < 4; ++mi)
#pragma unroll
    for (int nt = 0; nt < 6; ++nt) acc[mi][nt] = zf;

#pragma unroll
  for (int ks = 0; ks < 8; ++ks) {
    int k0 = ks * 32 + lk;
    short8v bfr[6];
#pragma unroll
    for (int nt = 0; nt < 6; ++nt) {
      int orow = (nt >> 1) * 248 + h * 31 + (nt & 1) * 16 + lr;  // <=744 (zero row)
      bfr[nt] = *(const short8v*)(wbf + (size_t)orow * 256 + k0);
    }
#pragma unroll
    for (int mi = 0; mi < 4; ++mi) {
      if (mi < mcount) {
        short8v a = *(const short8v*)(xb + (size_t)((mstart + mi) * 16 + lr) * 256 + k0);
#pragma unroll
        for (int nt = 0; nt < 6; ++nt)
          acc[mi][nt] = __builtin_amdgcn_mfma_f32_16x16x32_bf16(a, bfr[nt], acc[mi][nt], 0, 0, 0);
      }
    }
  }
  __syncthreads();   // zeroing visible before scatter
  // ---- epilogue: scatter D-frags into swizzled Qs/Ks/Vt ----
#pragma unroll
  for (int mi = 0; mi < 4; ++mi) {
    if (mi < mcount) {
#pragma unroll
      for (int nt = 0; nt < 6; ++nt) {
        int d = (nt & 1) * 16 + lr;
        if (d < D_) {
          int wi = nt >> 1;
          float bo = bias[wi * C_ + h * D_ + d];
#pragma unroll
          for (int r = 0; r < 4; ++r) {
            int pt = (mstart + mi) * 16 + (l >> 4) * 4 + r;
            int p = pt >> 2, t = pt & 3;
            if (p < P_) {
              float val = acc[mi][nt][r] + bo;
              int dh = d * 4 + t;
              if (wi == 0)
                *(unsigned short*)((char*)Qs + ((p * 256 + dh * 2) ^ ((p & 7) << 4))) = f2bf(val * scale);
              else if (wi == 1)
                *(unsigned short*)((char*)Ks + ((p * 256 + dh * 2) ^ ((p & 7) << 4))) = f2bf(val);
              else
                *(unsigned short*)((char*)Vt + ((dh * 128 + p * 2) ^ ((dh & 7) << 4))) = f2bf(val);
            }
          }
        }
      }
    }
  }
  __syncthreads();

  // ---- attention phase (proven R2 structure) ----
  const int arow = 16 * w + lr;
  const int prow0 = 16 * w + (l >> 4) * 4;

  f32x4 accS[4]; f32x4 accR[7];
#pragma unroll
  for (int n = 0; n < 4; ++n) accS[n] = zf;
#pragma unroll
  for (int n = 0; n < 7; ++n) accR[n] = zf;

#pragma unroll
  for (int ks = 0; ks < 4; ++ks) {
    int k0 = ks * 32 + lk;
    short8v a = *(const short8v*)((const char*)Qs + ((arow * 256 + 2 * k0) ^ ((arow & 7) << 4)));
#pragma unroll
    for (int n = 0; n < 4; ++n) {
      int brow = 16 * n + lr;
      short8v bb = *(const short8v*)((const char*)Ks + ((brow * 256 + 2 * k0) ^ ((brow & 7) << 4)));
      accS[n] = __builtin_amdgcn_mfma_f32_16x16x32_bf16(a, bb, accS[n], 0, 0, 0);
    }
#pragma unroll
    for (int n = 0; n < 7; ++n) {
      int rrow = 16 * n + lr;
      short8v bb = *(const short8v*)(relp + rrow * 128 + k0);
      accR[n] = __builtin_amdgcn_mfma_f32_16x16x32_bf16(a, bb, accR[n], 0, 0, 0);
    }
  }
#pragma unroll
  for (int n = 0; n < 7; ++n)
#pragma unroll
    for (int r = 0; r < 4; ++r)
      brs[(prow0 + r) * 112 + 16 * n + lr] = f2bf(accR[n][r]);
  __syncthreads();

  float sv[4][4];
#pragma unroll
  for (int n = 0; n < 4; ++n)
#pragma unroll
    for (int r = 0; r < 4; ++r) {
      int p = prow0 + r, j = 16 * n + lr;
      if (p < P_ && j < P_)
        sv[n][r] = accS[n][r] + bf2f(brs[p * 112 + (49 + j - p)]);
      else
        sv[n][r] = -1e30f;
    }
#pragma unroll
  for (int r = 0; r < 4; ++r) {
    float mm = fmaxf(fmaxf(sv[0][r], sv[1][r]), fmaxf(sv[2][r], sv[3][r]));
    mm = fmaxf(mm, __shfl_xor(mm, 1));
    mm = fmaxf(mm, __shfl_xor(mm, 2));
    mm = fmaxf(mm, __shfl_xor(mm, 4));
    mm = fmaxf(mm, __shfl_xor(mm, 8));
    float ss = 0.f;
#pragma unroll
    for (int n = 0; n < 4; ++n) { float e = __expf(sv[n][r] - mm); sv[n][r] = e; ss += e; }
    ss += __shfl_xor(ss, 1); ss += __shfl_xor(ss, 2);
    ss += __shfl_xor(ss, 4); ss += __shfl_xor(ss, 8);
    float inv = 1.f / ss;
#pragma unroll
    for (int n = 0; n < 4; ++n) sv[n][r] *= inv;
  }
#pragma unroll
  for (int n = 0; n < 4; ++n)
#pragma unroll
    for (int r = 0; r < 4; ++r) {
      int p = prow0 + r, j = 16 * n + lr;
      *(unsigned short*)((char*)Ps + ((p * 128 + 2 * j) ^ ((p & 7) << 4))) = f2bf(sv[n][r]);
    }
  __syncthreads();

  f32x4 accO[8];
#pragma unroll
  for (int n = 0; n < 8; ++n) accO[n] = zf;
#pragma unroll
  for (int ks = 0; ks < 2; ++ks) {
    int j0 = ks * 32 + lk;
    short8v a = *(const short8v*)((const char*)Ps + ((arow * 128 + 2 * j0) ^ ((arow & 7) << 4)));
#pragma unroll
    for (int n = 0; n < 8; ++n) {
      int vrow = 16 * n + lr;
      short8v bb = *(const short8v*)((const char*)Vt + ((vrow * 128 + 2 * j0) ^ ((vrow & 7) << 4)));
      accO[n] = __builtin_amdgcn_mfma_f32_16x16x32_bf16(a, bb, accO[n], 0, 0, 0);
    }
  }
#pragma unroll
  for (int n = 0; n < 8; ++n) {
    int dh = 16 * n + lr;
    if (dh < DH_) {
      int c = h * D_ + (dh >> 2), t = dh & 3;
#pragma unroll
      for (int r = 0; r < 4; ++r) {
        int p = prow0 + r;
        if (p < P_) {
          size_t idx = (((size_t)b * C_ + c) * P_ + p) * T_ + t;
          pre1[idx] = accO[n][r] + x[idx];
        }
      }
    }
  }
}

// BN batch-stat reduction: per channel over (B, PT). 256 threads = one b each.
__global__ __launch_bounds__(256) void bnstat_kernel(
    const float* __restrict__ t, const float* __restrict__ g, const float* __restrict__ be,
    float* __restrict__ a, float* __restrict__ bs, int nch) {
  const int c = blockIdx.x;
  const int tid = threadIdx.x;
  const float* base = t + ((size_t)tid * nch + c) * PT_;
  float s = 0.f, s2 = 0.f;
  for (int i = 0; i < PT_; i += 4) {
    float4 v = *(const float4*)(base + i);
    s += v.x + v.y + v.z + v.w;
    s2 += v.x*v.x + v.y*v.y + v.z*v.z + v.w*v.w;
  }
#pragma unroll
  for (int off = 32; off > 0; off >>= 1) {
    s += __shfl_down(s, off);
    s2 += __shfl_down(s2, off);
  }
  __shared__ float r1[4], r2[4];
  if ((tid & 63) == 0) { r1[tid>>6] = s; r2[tid>>6] = s2; }
  __syncthreads();
  if (tid == 0) {
    s = r1[0]+r1[1]+r1[2]+r1[3];
    s2 = r2[0]+r2[1]+r2[2]+r2[3];
    const float inv = 1.f / (float)(B_ * PT_);
    float m = s * inv;
    float var = s2 * inv - m * m;
    float ai = g[c] * rsqrtf(var + 1e-5f);
    a[c] = ai;
    bs[c] = be[c] - m * ai;
  }
}

// K4a: pre1 f32 [b][248][200] -> p1T bf16 [b*50+p][1024] (K = c*4+t', col992=1.0, rest 0)
__global__ __launch_bounds__(256) void p1t_kernel(const float* __restrict__ pre1,
                                                  unsigned short* __restrict__ p1T) {
  __shared__ float xs[64][205];
  const int b = blockIdx.x;
  const int tid = threadIdx.x;
  for (int c0 = 0; c0 < C_; c0 += 64) {
    int R = (C_ - c0 < 64) ? (C_ - c0) : 64;
    __syncthreads();
    for (int e = tid; e < R * 50; e += 256) {
      int row = e / 50, pq = e - (e / 50) * 50;
      float4 v = *(const float4*)(pre1 + ((size_t)b * C_ + c0 + row) * PT_ + pq * 4);
      xs[row][pq*4+0]=v.x; xs[row][pq*4+1]=v.y; xs[row][pq*4+2]=v.z; xs[row][pq*4+3]=v.w;
    }
    __syncthreads();
    for (int u = tid; u < 50 * R; u += 256) {
      int p = u / R, cl = u - (u / R) * R;
      ushort4 pk;
      pk.x = f2bf(xs[cl][p*4+0]); pk.y = f2bf(xs[cl][p*4+1]);
      pk.z = f2bf(xs[cl][p*4+2]); pk.w = f2bf(xs[cl][p*4+3]);
      *(ushort4*)(p1T + ((size_t)b*50 + p) * 1024 + (c0+cl)*4) = pk;
    }
  }
  for (int u = tid; u < 50 * 8; u += 256) {
    int p = u >> 3, g = u & 7;
    ushort4 val = make_ushort4(0,0,0,0);
    if (g == 0) val.x = 0x3F80;  // 1.0 bf16 const column
    *(ushort4*)(p1T + ((size_t)b*50 + p) * 1024 + 992 + g*4) = val;
  }
}

// K4b: build Wbig bf16 [64 n=(f,t)][1024 K=(c,t')+const] folding conv taps, a1, b1, bc
__global__ __launch_bounds__(256) void wcfe_kernel(
    const float* __restrict__ w1, const float* __restrict__ bc1,
    const float* __restrict__ w2, const float* __restrict__ bc2,
    const float* __restrict__ a1, const float* __restrict__ b1,
    unsigned short* __restrict__ Wbig) {
  const int n = blockIdx.x;
  const int f = n >> 2, t = n & 3;
  const int tid = threadIdx.x;
  __shared__ float red[256];
  float partial = 0.f;
  if (tid < C_) {
    int c = tid;
    float tv[4];
    float tsum = 0.f;
#pragma unroll
    for (int tp = 0; tp < 4; ++tp) {
      int dt = tp - t;
      float v = 0.f;
      if (f < 8) { if (dt >= -1 && dt <= 1) v = w1[(f * C_ + c) * 3 + dt + 1]; }
      else       { if (dt >= -2 && dt <= 2) v = w2[((f - 8) * C_ + c) * 5 + dt + 2]; }
      tv[tp] = v; tsum += v;
    }
    float ac = a1[c];
#pragma unroll
    for (int tp = 0; tp < 4; ++tp)
      Wbig[n * 1024 + c * 4 + tp] = f2bf(ac * tv[tp]);
    partial = b1[c] * tsum;
  } else {
#pragma unroll
    for (int tp = 0; tp < 4; ++tp) {
      int col = tid * 4 + tp;
      if (col > 992 && col < 1024) Wbig[n * 1024 + col] = 0;
    }
  }
  red[tid] = partial;
  __syncthreads();
  for (int s = 128; s > 0; s >>= 1) {
    if (tid < s) red[tid] += red[tid + s];
    __syncthreads();
  }
  if (tid == 0) {
    float bias = (f < 8) ? bc1[f] : bc2[f - 8];
    Wbig[n * 1024 + 992] = f2bf(bias + red[0]);
  }
}

// K4c: MFMA GEMM: y16[m=(b,p), n=(f,t)] = p1T[m] . Wbig[n].  M=12800, N=64, K=1024.
__global__ __launch_bounds__(256) void cfe12g_kernel(
    const unsigned short* __restrict__ p1T, const unsigned short* __restrict__ Wbig,
    float* __restrict__ y16) {
  const int tid = threadIdx.x;
  const int w = tid >> 6, l = tid & 63;
  const int lr = l & 15, lk = (l >> 4) * 8;
  const int m0 = blockIdx.x * 32;
  const f32x4 zf = {0.f, 0.f, 0.f, 0.f};
  f32x4 acc0 = zf, acc1 = zf;
  const unsigned short* wrow = Wbig + (size_t)(w * 16 + lr) * 1024;
#pragma unroll
  for (int ks = 0; ks < 32; ++ks) {
    int k0 = ks * 32 + lk;
    short8v bfr = *(const short8v*)(wrow + k0);
    short8v a0 = *(const short8v*)(p1T + (size_t)(m0 + lr) * 1024 + k0);
    short8v a1v = *(const short8v*)(p1T + (size_t)(m0 + 16 + lr) * 1024 + k0);
    acc0 = __builtin_amdgcn_mfma_f32_16x16x32_bf16(a0, bfr, acc0, 0, 0, 0);
    acc1 = __builtin_amdgcn_mfma_f32_16x16x32_bf16(a1v, bfr, acc1, 0, 0, 0);
  }
  const int n = w * 16 + lr, f = n >> 2, tt = n & 3;
#pragma unroll
  for (int mt = 0; mt < 2; ++mt) {
    f32x4 av = (mt == 0) ? acc0 : acc1;
#pragma unroll
    for (int r = 0; r < 4; ++r) {
      int m = m0 + mt * 16 + (l >> 4) * 4 + r;
      int b = m / 50, p = m - (m / 50) * 50;
      y16[((size_t)b * 16 + f) * PT_ + p * 4 + tt] = av[r];
    }
  }
}

// K6: ELU(BN_cfe(y16)) -> conv3 (16->248) + BN1-residual -> pre2
__global__ __launch_bounds__(256) void cfe3_kernel(
    const float* __restrict__ y16, const float* __restrict__ ac, const float* __restrict__ bcf,
    const float* __restrict__ w3, const float* __restrict__ bc3,
    const float* __restrict__ pre1, const float* __restrict__ a1, const float* __restrict__ b1,
    float* __restrict__ pre2) {
  const int b = blockIdx.x;
  const int tid = threadIdx.x;
  __shared__ float zs[16][PT_];
  __shared__ float w3s[C_][16];
  for (int i = tid; i < C_*16; i += 256) w3s[i >> 4][i & 15] = w3[i];
  for (int e = tid; e < 16*PT_; e += 256) {
    int f = e / PT_, pt = e - f * PT_;
    float v = y16[((size_t)b*16 + f) * PT_ + pt] * ac[f] + bcf[f];
    zs[f][pt] = (v > 0.f) ? v : (__expf(v) - 1.f);
  }
  __syncthreads();
  for (int e = tid; e < C_ * P_; e += 256) {
    int c = e / P_, p = e - (e / P_) * P_;
    float b3 = bc3[c];
    float4 o = make_float4(b3, b3, b3, b3);
#pragma unroll
    for (int f = 0; f < 16; ++f) {
      float wv = w3s[c][f];
      float4 z = *(const float4*)&zs[f][p*4];
      o.x += wv * z.x; o.y += wv * z.y; o.z += wv * z.z; o.w += wv * z.w;
    }
    size_t idx = (((size_t)b * C_ + c) * P_ + p) * T_;
    float4 xr = *(const float4*)(pre1 + idx);
    float a1c = a1[c], b1c = b1[c];
    o.x += xr.x * a1c + b1c;
    o.y += xr.y * a1c + b1c;
    o.z += xr.z * a1c + b1c;
    o.w += xr.w * a1c + b1c;
    *(float4*)(pre2 + idx) = o;
  }
}

// K8: apply BN2 -> out
__global__ __launch_bounds__(256) void bnapply_kernel(
    const float* __restrict__ pre2, const float* __restrict__ a, const float* __restrict__ bs,
    float* __restrict__ out) {
  int i = blockIdx.x * 256 + threadIdx.x;
  if (i < (B_*C_*PT_)/4) {
    int row = (i * 4) / PT_;
    int c = row % C_;
    float4 v = *(const float4*)(pre2 + (size_t)i * 4);
    float ai = a[c], bi = bs[c];
    float4 o = make_float4(v.x*ai+bi, v.y*ai+bi, v.z*ai+bi, v.w*ai+bi);
    *(float4*)(out + (size_t)i * 4) = o;
  }
}

extern "C" void kernel_launch(void* const* d_in, const int* in_sizes, int n_in,
                              void* d_out, int out_size, void* d_ws, size_t ws_size,
                              hipStream_t stream) {
  const float* x        = (const float*)d_in[0];
  const float* w_qkv    = (const float*)d_in[1];
  const float* b_qkv    = (const float*)d_in[2];
  const float* rel      = (const float*)d_in[3];
  const float* g1       = (const float*)d_in[4];
  const float* beta1    = (const float*)d_in[5];
  const float* w_c1     = (const float*)d_in[6];
  const float* bc1      = (const float*)d_in[7];
  const float* w_c2     = (const float*)d_in[8];
  const float* bc2      = (const float*)d_in[9];
  const float* g_cfe    = (const float*)d_in[10];
  const float* beta_cfe = (const float*)d_in[11];
  const float* w_c3     = (const float*)d_in[12];
  const float* bc3      = (const float*)d_in[13];
  const float* g2       = (const float*)d_in[14];
  const float* beta2    = (const float*)d_in[15];
  float* out = (float*)d_out;
  char* ws = (char*)d_ws;

  // ws layout (bytes):
  //   0          xT bf16 [256][208][256] (27,262,976)  [dead after fused_qa]
  //   27262976   wbf bf16 [768][256] (393,216)         [dead after fused_qa]
  //   27656192   p1T bf16 [12800][1024] (26,214,400)   [written by p1t, read by cfe12g]
  //   76185600   pre1 f32 (50,790,400)
  //   126976000  y16  f32 (3,276,800)
  //   130252800  relp bf16 [112][128] (28,672)
  //   130281472  Wbig bf16 [64][1024] (131,072)
  //   130412544  stats f32
  //   pre2 f32 (50,790,400) aliases ws+0 (xT/wbf/p1T all consumed before cfe3 writes)
  unsigned short* xT    = (unsigned short*)(ws);
  unsigned short* wbf   = (unsigned short*)(ws + 27262976);
  unsigned short* p1T   = (unsigned short*)(ws + 27656192);
  float* pre1           = (float*)(ws + 76185600);
  float* y16            = (float*)(ws + 126976000);
  unsigned short* relp  = (unsigned short*)(ws + 130252800);
  unsigned short* Wbig  = (unsigned short*)(ws + 130281472);
  float* st             = (float*)(ws + 130412544);
  float* a1 = st, *b1 = st + 256, *acf = st + 512, *bcf = st + 544, *a2 = st + 576, *b2 = st + 832;
  float* pre2           = (float*)ws;

  relcvt_kernel<<<56, 256, 0, stream>>>(rel, relp);
  wcvt_kernel<<<192, 256, 0, stream>>>(w_qkv, wbf);
  xt_kernel<<<dim3(16, 256), 256, 0, stream>>>(x, xT);
  fused_qa_kernel<<<2048, 256, 0, stream>>>(xT, wbf, b_qkv, relp, x, pre1);
  bnstat_kernel<<<248, 256, 0, stream>>>(pre1, g1, beta1, a1, b1, C_);
  p1t_kernel<<<256, 256, 0, stream>>>(pre1, p1T);
  wcfe_kernel<<<64, 256, 0, stream>>>(w_c1, bc1, w_c2, bc2, a1, b1, Wbig);
  cfe12g_kernel<<<400, 256, 0, stream>>>(p1T, Wbig, y16);
  bnstat_kernel<<<16, 256, 0, stream>>>(y16, g_cfe, beta_cfe, acf, bcf, 16);
  cfe3_kernel<<<256, 256, 0, stream>>>(y16, acf, bcf, w_c3, bc3, pre1, a1, b1, pre2);
  bnstat_kernel<<<248, 256, 0, stream>>>(pre2, g2, beta2, a2, b2, C_);
  bnapply_kernel<<<12400, 256, 0, stream>>>(pre2, a2, b2, out);
}

// Round 11
// 397.799 us; speedup vs baseline: 1.1275x; 1.0024x over previous
//
#include <hip/hip_runtime.h>

#define B_ 256
#define C_ 248
#define P_ 50
#define T_ 4
#define H_ 8
#define D_ 31
#define DH_ 124
#define PT_ 200
#define O3_ 744

typedef __attribute__((ext_vector_type(8))) short short8v;
typedef __attribute__((ext_vector_type(4))) float f32x4;

__device__ __forceinline__ float bf2f(unsigned short u) {
  union { unsigned int i; float f; } v; v.i = ((unsigned int)u) << 16; return v.f;
}
__device__ __forceinline__ unsigned short f2bf(float f) {
  union { float f; unsigned int i; } v; v.f = f;
  unsigned int r = v.i + 0x7fffu + ((v.i >> 16) & 1u);
  return (unsigned short)(r >> 16);
}

// K0: rel_emb fp32 -> bf16, zero-padded to [112][128]
__global__ void relcvt_kernel(const float* __restrict__ rel, unsigned short* __restrict__ out) {
  int i = blockIdx.x * 256 + threadIdx.x;
  if (i < 112 * 128) {
    int r = i >> 7, k = i & 127;
    out[i] = (r < 99 && k < DH_) ? f2bf(rel[r * DH_ + k]) : (unsigned short)0;
  }
}

// K0b: w_qkv fp32 [744][248] -> bf16 zero-padded [768][256]
__global__ void wcvt_kernel(const float* __restrict__ w, unsigned short* __restrict__ wbf) {
  int i = blockIdx.x * 256 + threadIdx.x;
  if (i < 768 * 64) {
    int o = i >> 6, c = (i & 63) * 4;
    ushort4 val = make_ushort4(0, 0, 0, 0);
    if (o < O3_ && c < C_) {
      float4 wv = *(const float4*)(w + (size_t)o * C_ + c);
      val.x = f2bf(wv.x); val.y = f2bf(wv.y); val.z = f2bf(wv.z); val.w = f2bf(wv.w);
    }
    *(ushort4*)(wbf + (size_t)o * 256 + c) = val;
  }
}

// K0c: x fp32 [b][248][200] -> xT bf16 [b][208][256] (pt-major, zero-padded)
__global__ __launch_bounds__(256) void xt_kernel(const float* __restrict__ x,
                                                 unsigned short* __restrict__ xT) {
  __shared__ float xs[64 * 65];
  const int tid = threadIdx.x;
  const int pt0 = (blockIdx.x & 3) * 64;
  const int c0 = (blockIdx.x >> 2) * 64;
  const int b = blockIdx.y;
#pragma unroll
  for (int pass = 0; pass < 4; ++pass) {
    int row = pass * 16 + (tid >> 4);
    int ptl4 = (tid & 15) * 4;
    int c = c0 + row, pt = pt0 + ptl4;
    float4 v = make_float4(0.f, 0.f, 0.f, 0.f);
    if (c < C_) {
      const float* src = x + ((size_t)b * C_ + c) * PT_ + pt;
      if (pt + 3 < PT_) v = *(const float4*)src;
      else {
        if (pt + 0 < PT_) v.x = src[0];
        if (pt + 1 < PT_) v.y = src[1];
        if (pt + 2 < PT_) v.z = src[2];
        if (pt + 3 < PT_) v.w = src[3];
      }
    }
    xs[row * 65 + ptl4 + 0] = v.x; xs[row * 65 + ptl4 + 1] = v.y;
    xs[row * 65 + ptl4 + 2] = v.z; xs[row * 65 + ptl4 + 3] = v.w;
  }
  __syncthreads();
#pragma unroll
  for (int pass = 0; pass < 4; ++pass) {
    int ptl = pass * 16 + (tid >> 4);
    int cl4 = (tid & 15) * 4;
    int pt = pt0 + ptl;
    if (pt < 208) {
      ushort4 pk;
      pk.x = f2bf(xs[(cl4 + 0) * 65 + ptl]);
      pk.y = f2bf(xs[(cl4 + 1) * 65 + ptl]);
      pk.z = f2bf(xs[(cl4 + 2) * 65 + ptl]);
      pk.w = f2bf(xs[(cl4 + 3) * 65 + ptl]);
      *(ushort4*)(xT + ((size_t)b * 208 + pt) * 256 + c0 + cl4) = pk;
    }
  }
}

// K1: FUSED qkv-GEMM + attention per (b,h), LDS time-shared to 48KB (3 blocks/CU):
//   RA: Qs [64][128] during GEMM+QK, then Ps [64][64]
//   RB: Ks [64][128] during GEMM+QK, then bias_s [64][64] (diagonal-shifted rel bias)
//   RC: Vt [128][64] throughout
// Q/K epilogue writes vectorized (ushort4 = 4 t-values of one (p,d)).
__global__ __launch_bounds__(256) void fused_qa_kernel(
    const unsigned short* __restrict__ xT, const unsigned short* __restrict__ wbf,
    const float* __restrict__ bias, const unsigned short* __restrict__ relp,
    const float* __restrict__ x, float* __restrict__ pre1) {
  __shared__ __align__(16) unsigned short RA[64 * 128];
  __shared__ __align__(16) unsigned short RB[64 * 128];
  __shared__ __align__(16) unsigned short RC[128 * 64];
  const int tid = threadIdx.x;
  const int xcd = blockIdx.x & 7, slot = blockIdx.x >> 3;
  const int b = xcd * 32 + (slot >> 3), h = slot & 7;
  const unsigned short* xb = xT + (size_t)b * 208 * 256;
  const int w = tid >> 6, l = tid & 63;
  const int lr = l & 15, lk = (l >> 4) * 8;
  const int mstart = (w == 0) ? 0 : (1 + 3 * w);   // {0,4,7,10}
  const int mcount = (w == 0) ? 4 : 3;
  const float scale = 0.17960530202677491f;

  // zero RA/RB/RC (padding must be 0; valid entries overwritten by scatter)
  {
    float4 z = make_float4(0.f, 0.f, 0.f, 0.f);
    float4* z1 = (float4*)RA; float4* z2 = (float4*)RB; float4* z3 = (float4*)RC;
    for (int i = tid; i < 1024; i += 256) { z1[i] = z; z2[i] = z; z3[i] = z; }
  }

  // ---- GEMM phase (global reads only) ----
  const f32x4 zf = {0.f, 0.f, 0.f, 0.f};
  f32x4 acc[4][6];
#pragma unroll
  for (int mi = 0; mi < 4; ++mi)
#pragma unroll
    for (int nt = 0; nt < 6; ++nt) acc[mi][nt] = zf;

#pragma unroll
  for (int ks = 0; ks < 8; ++ks) {
    int k0 = ks * 32 + lk;
    short8v bfr[6];
#pragma unroll
    for (int nt = 0; nt < 6; ++nt) {
      int orow = (nt >> 1) * 248 + h * 31 + (nt & 1) * 16 + lr;  // <=744 (zero row)
      bfr[nt] = *(const short8v*)(wbf + (size_t)orow * 256 + k0);
    }
#pragma unroll
    for (int mi = 0; mi < 4; ++mi) {
      if (mi < mcount) {
        short8v a = *(const short8v*)(xb + (size_t)((mstart + mi) * 16 + lr) * 256 + k0);
#pragma unroll
        for (int nt = 0; nt < 6; ++nt)
          acc[mi][nt] = __builtin_amdgcn_mfma_f32_16x16x32_bf16(a, bfr[nt], acc[mi][nt], 0, 0, 0);
      }
    }
  }
  __syncthreads();   // zeroing visible before scatter
  // ---- epilogue: scatter D-frags into swizzled Qs(RA)/Ks(RB)/Vt(RC) ----
  // For fixed (mi,nt): p = tile*4 + (l>>4) constant over r, t=r -> dh=4d..4d+3 contiguous.
#pragma unroll
  for (int mi = 0; mi < 4; ++mi) {
    if (mi < mcount) {
      int p = (mstart + mi) * 4 + (l >> 4);
      if (p < P_) {
#pragma unroll
        for (int nt = 0; nt < 6; ++nt) {
          int d = (nt & 1) * 16 + lr;
          if (d < D_) {
            int wi = nt >> 1;
            float bo = bias[wi * C_ + h * D_ + d];
            f32x4 av = acc[mi][nt];
            if (wi == 2) {
#pragma unroll
              for (int r = 0; r < 4; ++r) {
                int dh = d * 4 + r;
                *(unsigned short*)((char*)RC + ((dh * 128 + p * 2) ^ ((dh & 7) << 4))) = f2bf(av[0] + bo);
                av = __builtin_shufflevector(av, av, 1, 2, 3, 0);
              }
            } else if (wi == 0) {
              ushort4 pk;
              pk.x = f2bf((av[0] + bo) * scale); pk.y = f2bf((av[1] + bo) * scale);
              pk.z = f2bf((av[2] + bo) * scale); pk.w = f2bf((av[3] + bo) * scale);
              *(ushort4*)((char*)RA + ((p * 256 + d * 8) ^ ((p & 7) << 4))) = pk;
            } else {
              ushort4 pk;
              pk.x = f2bf(av[0] + bo); pk.y = f2bf(av[1] + bo);
              pk.z = f2bf(av[2] + bo); pk.w = f2bf(av[3] + bo);
              *(ushort4*)((char*)RB + ((p * 256 + d * 8) ^ ((p & 7) << 4))) = pk;
            }
          }
        }
      }
    }
  }
  __syncthreads();

  // ---- QK^T + rel-bias MFMA (reads RA=Qs, RB=Ks, relp) ----
  const int arow = 16 * w + lr;
  const int prow0 = 16 * w + (l >> 4) * 4;

  f32x4 accS[4]; f32x4 accR[7];
#pragma unroll
  for (int n = 0; n < 4; ++n) accS[n] = zf;
#pragma unroll
  for (int n = 0; n < 7; ++n) accR[n] = zf;

#pragma unroll
  for (int ks = 0; ks < 4; ++ks) {
    int k0 = ks * 32 + lk;
    short8v a = *(const short8v*)((const char*)RA + ((arow * 256 + 2 * k0) ^ ((arow & 7) << 4)));
#pragma unroll
    for (int n = 0; n < 4; ++n) {
      int brow = 16 * n + lr;
      short8v bb = *(const short8v*)((const char*)RB + ((brow * 256 + 2 * k0) ^ ((brow & 7) << 4)));
      accS[n] = __builtin_amdgcn_mfma_f32_16x16x32_bf16(a, bb, accS[n], 0, 0, 0);
    }
#pragma unroll
    for (int n = 0; n < 7; ++n) {
      int rrow = 16 * n + lr;
      short8v bb = *(const short8v*)(relp + rrow * 128 + k0);
      accR[n] = __builtin_amdgcn_mfma_f32_16x16x32_bf16(a, bb, accR[n], 0, 0, 0);
    }
  }
  __syncthreads();   // all waves done reading RB before bias_s overwrites it

  // ---- diagonal-shifted bias store: bias_s[p][j] = brel[p][49+j-p] ----
  unsigned short* bias_s = RB;   // [64][64] bf16
#pragma unroll
  for (int n = 0; n < 7; ++n)
#pragma unroll
    for (int r = 0; r < 4; ++r) {
      int p = prow0 + r;
      int j = 16 * n + lr - 49 + p;
      if (p < P_ && j >= 0 && j < P_)
        bias_s[p * 64 + j] = f2bf(accR[n][r]);
    }
  __syncthreads();

  // ---- softmax (reads bias_s=RB, writes Ps into RA) ----
  float sv[4][4];
#pragma unroll
  for (int n = 0; n < 4; ++n)
#pragma unroll
    for (int r = 0; r < 4; ++r) {
      int p = prow0 + r, j = 16 * n + lr;
      if (p < P_ && j < P_)
        sv[n][r] = accS[n][r] + bf2f(bias_s[p * 64 + j]);
      else
        sv[n][r] = -1e30f;
    }
#pragma unroll
  for (int r = 0; r < 4; ++r) {
    float mm = fmaxf(fmaxf(sv[0][r], sv[1][r]), fmaxf(sv[2][r], sv[3][r]));
    mm = fmaxf(mm, __shfl_xor(mm, 1));
    mm = fmaxf(mm, __shfl_xor(mm, 2));
    mm = fmaxf(mm, __shfl_xor(mm, 4));
    mm = fmaxf(mm, __shfl_xor(mm, 8));
    float ss = 0.f;
#pragma unroll
    for (int n = 0; n < 4; ++n) { float e = __expf(sv[n][r] - mm); sv[n][r] = e; ss += e; }
    ss += __shfl_xor(ss, 1); ss += __shfl_xor(ss, 2);
    ss += __shfl_xor(ss, 4); ss += __shfl_xor(ss, 8);
    float inv = 1.f / ss;
#pragma unroll
    for (int n = 0; n < 4; ++n) sv[n][r] *= inv;
  }
#pragma unroll
  for (int n = 0; n < 4; ++n)
#pragma unroll
    for (int r = 0; r < 4; ++r) {
      int p = prow0 + r, j = 16 * n + lr;
      *(unsigned short*)((char*)RA + ((p * 128 + 2 * j) ^ ((p & 7) << 4))) = f2bf(sv[n][r]);
    }
  __syncthreads();

  // ---- PV (reads Ps=RA, Vt=RC) ----
  f32x4 accO[8];
#pragma unroll
  for (int n = 0; n < 8; ++n) accO[n] = zf;
#pragma unroll
  for (int ks = 0; ks < 2; ++ks) {
    int j0 = ks * 32 + lk;
    short8v a = *(const short8v*)((const char*)RA + ((arow * 128 + 2 * j0) ^ ((arow & 7) << 4)));
#pragma unroll
    for (int n = 0; n < 8; ++n) {
      int vrow = 16 * n + lr;
      short8v bb = *(const short8v*)((const char*)RC + ((vrow * 128 + 2 * j0) ^ ((vrow & 7) << 4)));
      accO[n] = __builtin_amdgcn_mfma_f32_16x16x32_bf16(a, bb, accO[n], 0, 0, 0);
    }
  }
#pragma unroll
  for (int n = 0; n < 8; ++n) {
    int dh = 16 * n + lr;
    if (dh < DH_) {
      int c = h * D_ + (dh >> 2), t = dh & 3;
#pragma unroll
      for (int r = 0; r < 4; ++r) {
        int p = prow0 + r;
        if (p < P_) {
          size_t idx = (((size_t)b * C_ + c) * P_ + p) * T_ + t;
          pre1[idx] = accO[n][r] + x[idx];
        }
      }
    }
  }
}

// BN batch-stat reduction: per channel over (B, PT). 256 threads = one b each.
__global__ __launch_bounds__(256) void bnstat_kernel(
    const float* __restrict__ t, const float* __restrict__ g, const float* __restrict__ be,
    float* __restrict__ a, float* __restrict__ bs, int nch) {
  const int c = blockIdx.x;
  const int tid = threadIdx.x;
  const float* base = t + ((size_t)tid * nch + c) * PT_;
  float s = 0.f, s2 = 0.f;
  for (int i = 0; i < PT_; i += 4) {
    float4 v = *(const float4*)(base + i);
    s += v.x + v.y + v.z + v.w;
    s2 += v.x*v.x + v.y*v.y + v.z*v.z + v.w*v.w;
  }
#pragma unroll
  for (int off = 32; off > 0; off >>= 1) {
    s += __shfl_down(s, off);
    s2 += __shfl_down(s2, off);
  }
  __shared__ float r1[4], r2[4];
  if ((tid & 63) == 0) { r1[tid>>6] = s; r2[tid>>6] = s2; }
  __syncthreads();
  if (tid == 0) {
    s = r1[0]+r1[1]+r1[2]+r1[3];
    s2 = r2[0]+r2[1]+r2[2]+r2[3];
    const float inv = 1.f / (float)(B_ * PT_);
    float m = s * inv;
    float var = s2 * inv - m * m;
    float ai = g[c] * rsqrtf(var + 1e-5f);
    a[c] = ai;
    bs[c] = be[c] - m * ai;
  }
}

// K4a: pre1 f32 [b][248][200] -> p1T bf16 [b*50+p][1024] (K = c*4+t', col992=1.0, rest 0)
__global__ __launch_bounds__(256) void p1t_kernel(const float* __restrict__ pre1,
                                                  unsigned short* __restrict__ p1T) {
  __shared__ float xs[64][205];
  const int b = blockIdx.x;
  const int tid = threadIdx.x;
  for (int c0 = 0; c0 < C_; c0 += 64) {
    int R = (C_ - c0 < 64) ? (C_ - c0) : 64;
    __syncthreads();
    for (int e = tid; e < R * 50; e += 256) {
      int row = e / 50, pq = e - (e / 50) * 50;
      float4 v = *(const float4*)(pre1 + ((size_t)b * C_ + c0 + row) * PT_ + pq * 4);
      xs[row][pq*4+0]=v.x; xs[row][pq*4+1]=v.y; xs[row][pq*4+2]=v.z; xs[row][pq*4+3]=v.w;
    }
    __syncthreads();
    for (int u = tid; u < 50 * R; u += 256) {
      int p = u / R, cl = u - (u / R) * R;
      ushort4 pk;
      pk.x = f2bf(xs[cl][p*4+0]); pk.y = f2bf(xs[cl][p*4+1]);
      pk.z = f2bf(xs[cl][p*4+2]); pk.w = f2bf(xs[cl][p*4+3]);
      *(ushort4*)(p1T + ((size_t)b*50 + p) * 1024 + (c0+cl)*4) = pk;
    }
  }
  for (int u = tid; u < 50 * 8; u += 256) {
    int p = u >> 3, g = u & 7;
    ushort4 val = make_ushort4(0,0,0,0);
    if (g == 0) val.x = 0x3F80;  // 1.0 bf16 const column
    *(ushort4*)(p1T + ((size_t)b*50 + p) * 1024 + 992 + g*4) = val;
  }
}

// K4b: build Wbig bf16 [64 n=(f,t)][1024 K=(c,t')+const] folding conv taps, a1, b1, bc
__global__ __launch_bounds__(256) void wcfe_kernel(
    const float* __restrict__ w1, const float* __restrict__ bc1,
    const float* __restrict__ w2, const float* __restrict__ bc2,
    const float* __restrict__ a1, const float* __restrict__ b1,
    unsigned short* __restrict__ Wbig) {
  const int n = blockIdx.x;
  const int f = n >> 2, t = n & 3;
  const int tid = threadIdx.x;
  __shared__ float red[256];
  float partial = 0.f;
  if (tid < C_) {
    int c = tid;
    float tv[4];
    float tsum = 0.f;
#pragma unroll
    for (int tp = 0; tp < 4; ++tp) {
      int dt = tp - t;
      float v = 0.f;
      if (f < 8) { if (dt >= -1 && dt <= 1) v = w1[(f * C_ + c) * 3 + dt + 1]; }
      else       { if (dt >= -2 && dt <= 2) v = w2[((f - 8) * C_ + c) * 5 + dt + 2]; }
      tv[tp] = v; tsum += v;
    }
    float ac = a1[c];
#pragma unroll
    for (int tp = 0; tp < 4; ++tp)
      Wbig[n * 1024 + c * 4 + tp] = f2bf(ac * tv[tp]);
    partial = b1[c] * tsum;
  } else {
#pragma unroll
    for (int tp = 0; tp < 4; ++tp) {
      int col = tid * 4 + tp;
      if (col > 992 && col < 1024) Wbig[n * 1024 + col] = 0;
    }
  }
  red[tid] = partial;
  __syncthreads();
  for (int s = 128; s > 0; s >>= 1) {
    if (tid < s) red[tid] += red[tid + s];
    __syncthreads();
  }
  if (tid == 0) {
    float bias = (f < 8) ? bc1[f] : bc2[f - 8];
    Wbig[n * 1024 + 992] = f2bf(bias + red[0]);
  }
}

// K4c: MFMA GEMM: y16[m=(b,p), n=(f,t)] = p1T[m] . Wbig[n].  M=12800, N=64, K=1024.
__global__ __launch_bounds__(256) void cfe12g_kernel(
    const unsigned short* __restrict__ p1T, const unsigned short* __restrict__ Wbig,
    float* __restrict__ y16) {
  const int tid = threadIdx.x;
  const int w = tid >> 6, l = tid & 63;
  const int lr = l & 15, lk = (l >> 4) * 8;
  const int m0 = blockIdx.x * 32;
  const f32x4 zf = {0.f, 0.f, 0.f, 0.f};
  f32x4 acc0 = zf, acc1 = zf;
  const unsigned short* wrow = Wbig + (size_t)(w * 16 + lr) * 1024;
#pragma unroll
  for (int ks = 0; ks < 32; ++ks) {
    int k0 = ks * 32 + lk;
    short8v bfr = *(const short8v*)(wrow + k0);
    short8v a0 = *(const short8v*)(p1T + (size_t)(m0 + lr) * 1024 + k0);
    short8v a1v = *(const short8v*)(p1T + (size_t)(m0 + 16 + lr) * 1024 + k0);
    acc0 = __builtin_amdgcn_mfma_f32_16x16x32_bf16(a0, bfr, acc0, 0, 0, 0);
    acc1 = __builtin_amdgcn_mfma_f32_16x16x32_bf16(a1v, bfr, acc1, 0, 0, 0);
  }
  const int n = w * 16 + lr, f = n >> 2, tt = n & 3;
#pragma unroll
  for (int mt = 0; mt < 2; ++mt) {
    f32x4 av = (mt == 0) ? acc0 : acc1;
#pragma unroll
    for (int r = 0; r < 4; ++r) {
      int m = m0 + mt * 16 + (l >> 4) * 4 + r;
      int b = m / 50, p = m - (m / 50) * 50;
      y16[((size_t)b * 16 + f) * PT_ + p * 4 + tt] = av[r];
    }
  }
}

// K6: ELU(BN_cfe(y16)) -> conv3 (16->248) + BN1-residual -> pre2
__global__ __launch_bounds__(256) void cfe3_kernel(
    const float* __restrict__ y16, const float* __restrict__ ac, const float* __restrict__ bcf,
    const float* __restrict__ w3, const float* __restrict__ bc3,
    const float* __restrict__ pre1, const float* __restrict__ a1, const float* __restrict__ b1,
    float* __restrict__ pre2) {
  const int b = blockIdx.x;
  const int tid = threadIdx.x;
  __shared__ float zs[16][PT_];
  __shared__ float w3s[C_][16];
  for (int i = tid; i < C_*16; i += 256) w3s[i >> 4][i & 15] = w3[i];
  for (int e = tid; e < 16*PT_; e += 256) {
    int f = e / PT_, pt = e - f * PT_;
    float v = y16[((size_t)b*16 + f) * PT_ + pt] * ac[f] + bcf[f];
    zs[f][pt] = (v > 0.f) ? v : (__expf(v) - 1.f);
  }
  __syncthreads();
  for (int e = tid; e < C_ * P_; e += 256) {
    int c = e / P_, p = e - (e / P_) * P_;
    float b3 = bc3[c];
    float4 o = make_float4(b3, b3, b3, b3);
#pragma unroll
    for (int f = 0; f < 16; ++f) {
      float wv = w3s[c][f];
      float4 z = *(const float4*)&zs[f][p*4];
      o.x += wv * z.x; o.y += wv * z.y; o.z += wv * z.z; o.w += wv * z.w;
    }
    size_t idx = (((size_t)b * C_ + c) * P_ + p) * T_;
    float4 xr = *(const float4*)(pre1 + idx);
    float a1c = a1[c], b1c = b1[c];
    o.x += xr.x * a1c + b1c;
    o.y += xr.y * a1c + b1c;
    o.z += xr.z * a1c + b1c;
    o.w += xr.w * a1c + b1c;
    *(float4*)(pre2 + idx) = o;
  }
}

// K8: apply BN2 -> out
__global__ __launch_bounds__(256) void bnapply_kernel(
    const float* __restrict__ pre2, const float* __restrict__ a, const float* __restrict__ bs,
    float* __restrict__ out) {
  int i = blockIdx.x * 256 + threadIdx.x;
  if (i < (B_*C_*PT_)/4) {
    int row = (i * 4) / PT_;
    int c = row % C_;
    float4 v = *(const float4*)(pre2 + (size_t)i * 4);
    float ai = a[c], bi = bs[c];
    float4 o = make_float4(v.x*ai+bi, v.y*ai+bi, v.z*ai+bi, v.w*ai+bi);
    *(float4*)(out + (size_t)i * 4) = o;
  }
}

extern "C" void kernel_launch(void* const* d_in, const int* in_sizes, int n_in,
                              void* d_out, int out_size, void* d_ws, size_t ws_size,
                              hipStream_t stream) {
  const float* x        = (const float*)d_in[0];
  const float* w_qkv    = (const float*)d_in[1];
  const float* b_qkv    = (const float*)d_in[2];
  const float* rel      = (const float*)d_in[3];
  const float* g1       = (const float*)d_in[4];
  const float* beta1    = (const float*)d_in[5];
  const float* w_c1     = (const float*)d_in[6];
  const float* bc1      = (const float*)d_in[7];
  const float* w_c2     = (const float*)d_in[8];
  const float* bc2      = (const float*)d_in[9];
  const float* g_cfe    = (const float*)d_in[10];
  const float* beta_cfe = (const float*)d_in[11];
  const float* w_c3     = (const float*)d_in[12];
  const float* bc3      = (const float*)d_in[13];
  const float* g2       = (const float*)d_in[14];
  const float* beta2    = (const float*)d_in[15];
  float* out = (float*)d_out;
  char* ws = (char*)d_ws;

  // ws layout (bytes):
  //   0          xT bf16 [256][208][256] (27,262,976)  [dead after fused_qa]
  //   27262976   wbf bf16 [768][256] (393,216)         [dead after fused_qa]
  //   27656192   p1T bf16 [12800][1024] (26,214,400)   [written by p1t, read by cfe12g]
  //   76185600   pre1 f32 (50,790,400)
  //   126976000  y16  f32 (3,276,800)
  //   130252800  relp bf16 [112][128] (28,672)
  //   130281472  Wbig bf16 [64][1024] (131,072)
  //   130412544  stats f32
  //   pre2 f32 (50,790,400) aliases ws+0 (xT/wbf/p1T all consumed before cfe3 writes)
  unsigned short* xT    = (unsigned short*)(ws);
  unsigned short* wbf   = (unsigned short*)(ws + 27262976);
  unsigned short* p1T   = (unsigned short*)(ws + 27656192);
  float* pre1           = (float*)(ws + 76185600);
  float* y16            = (float*)(ws + 126976000);
  unsigned short* relp  = (unsigned short*)(ws + 130252800);
  unsigned short* Wbig  = (unsigned short*)(ws + 130281472);
  float* st             = (float*)(ws + 130412544);
  float* a1 = st, *b1 = st + 256, *acf = st + 512, *bcf = st + 544, *a2 = st + 576, *b2 = st + 832;
  float* pre2           = (float*)ws;

  relcvt_kernel<<<56, 256, 0, stream>>>(rel, relp);
  wcvt_kernel<<<192, 256, 0, stream>>>(w_qkv, wbf);
  xt_kernel<<<dim3(16, 256), 256, 0, stream>>>(x, xT);
  fused_qa_kernel<<<2048, 256, 0, stream>>>(xT, wbf, b_qkv, relp, x, pre1);
  bnstat_kernel<<<248, 256, 0, stream>>>(pre1, g1, beta1, a1, b1, C_);
  p1t_kernel<<<256, 256, 0, stream>>>(pre1, p1T);
  wcfe_kernel<<<64, 256, 0, stream>>>(w_c1, bc1, w_c2, bc2, a1, b1, Wbig);
  cfe12g_kernel<<<400, 256, 0, stream>>>(p1T, Wbig, y16);
  bnstat_kernel<<<16, 256, 0, stream>>>(y16, g_cfe, beta_cfe, acf, bcf, 16);
  cfe3_kernel<<<256, 256, 0, stream>>>(y16, acf, bcf, w_c3, bc3, pre1, a1, b1, pre2);
  bnstat_kernel<<<248, 256, 0, stream>>>(pre2, g2, beta2, a2, b2, C_);
  bnapply_kernel<<<12400, 256, 0, stream>>>(pre2, a2, b2, out);
}

// Round 12
// 367.032 us; speedup vs baseline: 1.2220x; 1.0838x over previous
//
#include <hip/hip_runtime.h>

#define B_ 256
#define C_ 248
#define P_ 50
#define T_ 4
#define H_ 8
#define D_ 31
#define DH_ 124
#define PT_ 200
#define O3_ 744

typedef __attribute__((ext_vector_type(8))) short short8v;
typedef __attribute__((ext_vector_type(4))) float f32x4;

__device__ __forceinline__ float bf2f(unsigned short u) {
  union { unsigned int i; float f; } v; v.i = ((unsigned int)u) << 16; return v.f;
}
__device__ __forceinline__ unsigned short f2bf(float f) {
  union { float f; unsigned int i; } v; v.f = f;
  unsigned int r = v.i + 0x7fffu + ((v.i >> 16) & 1u);
  return (unsigned short)(r >> 16);
}

// K0: rel_emb fp32 -> bf16, zero-padded to [112][128]
__global__ void relcvt_kernel(const float* __restrict__ rel, unsigned short* __restrict__ out) {
  int i = blockIdx.x * 256 + threadIdx.x;
  if (i < 112 * 128) {
    int r = i >> 7, k = i & 127;
    out[i] = (r < 99 && k < DH_) ? f2bf(rel[r * DH_ + k]) : (unsigned short)0;
  }
}

// K0b: w_qkv fp32 [744][248] -> bf16 zero-padded [768][256]
__global__ void wcvt_kernel(const float* __restrict__ w, unsigned short* __restrict__ wbf) {
  int i = blockIdx.x * 256 + threadIdx.x;
  if (i < 768 * 64) {
    int o = i >> 6, c = (i & 63) * 4;
    ushort4 val = make_ushort4(0, 0, 0, 0);
    if (o < O3_ && c < C_) {
      float4 wv = *(const float4*)(w + (size_t)o * C_ + c);
      val.x = f2bf(wv.x); val.y = f2bf(wv.y); val.z = f2bf(wv.z); val.w = f2bf(wv.w);
    }
    *(ushort4*)(wbf + (size_t)o * 256 + c) = val;
  }
}

// K0c: x fp32 [b][248][200] -> xT bf16 [b][208][256] (pt-major, zero-padded)
__global__ __launch_bounds__(256) void xt_kernel(const float* __restrict__ x,
                                                 unsigned short* __restrict__ xT) {
  __shared__ float xs[64 * 65];
  const int tid = threadIdx.x;
  const int pt0 = (blockIdx.x & 3) * 64;
  const int c0 = (blockIdx.x >> 2) * 64;
  const int b = blockIdx.y;
#pragma unroll
  for (int pass = 0; pass < 4; ++pass) {
    int row = pass * 16 + (tid >> 4);
    int ptl4 = (tid & 15) * 4;
    int c = c0 + row, pt = pt0 + ptl4;
    float4 v = make_float4(0.f, 0.f, 0.f, 0.f);
    if (c < C_) {
      const float* src = x + ((size_t)b * C_ + c) * PT_ + pt;
      if (pt + 3 < PT_) v = *(const float4*)src;
      else {
        if (pt + 0 < PT_) v.x = src[0];
        if (pt + 1 < PT_) v.y = src[1];
        if (pt + 2 < PT_) v.z = src[2];
        if (pt + 3 < PT_) v.w = src[3];
      }
    }
    xs[row * 65 + ptl4 + 0] = v.x; xs[row * 65 + ptl4 + 1] = v.y;
    xs[row * 65 + ptl4 + 2] = v.z; xs[row * 65 + ptl4 + 3] = v.w;
  }
  __syncthreads();
#pragma unroll
  for (int pass = 0; pass < 4; ++pass) {
    int ptl = pass * 16 + (tid >> 4);
    int cl4 = (tid & 15) * 4;
    int pt = pt0 + ptl;
    if (pt < 208) {
      ushort4 pk;
      pk.x = f2bf(xs[(cl4 + 0) * 65 + ptl]);
      pk.y = f2bf(xs[(cl4 + 1) * 65 + ptl]);
      pk.z = f2bf(xs[(cl4 + 2) * 65 + ptl]);
      pk.w = f2bf(xs[(cl4 + 3) * 65 + ptl]);
      *(ushort4*)(xT + ((size_t)b * 208 + pt) * 256 + c0 + cl4) = pk;
    }
  }
}

// K1: FUSED qkv-GEMM + attention per (b,h). LDS 48KB time-shared (RA/RB/RC).
// Epilogue writes p1T bf16 directly (pre1 never materialized in f32) and
// reduces per-channel BN1 partial stats -> partial1[(b*8+h)][62].
__global__ __launch_bounds__(256) void fused_qa_kernel(
    const unsigned short* __restrict__ xT, const unsigned short* __restrict__ wbf,
    const float* __restrict__ bias, const unsigned short* __restrict__ relp,
    const float* __restrict__ x, unsigned short* __restrict__ p1T,
    float* __restrict__ partial1) {
  __shared__ __align__(16) unsigned short RA[64 * 128];
  __shared__ __align__(16) unsigned short RB[64 * 128];
  __shared__ __align__(16) unsigned short RC[128 * 64];
  const int tid = threadIdx.x;
  const int xcd = blockIdx.x & 7, slot = blockIdx.x >> 3;
  const int b = xcd * 32 + (slot >> 3), h = slot & 7;
  const unsigned short* xb = xT + (size_t)b * 208 * 256;
  const int w = tid >> 6, l = tid & 63;
  const int lr = l & 15, lk = (l >> 4) * 8;
  const int mstart = (w == 0) ? 0 : (1 + 3 * w);   // {0,4,7,10}
  const int mcount = (w == 0) ? 4 : 3;
  const float scale = 0.17960530202677491f;

  {
    float4 z = make_float4(0.f, 0.f, 0.f, 0.f);
    float4* z1 = (float4*)RA; float4* z2 = (float4*)RB; float4* z3 = (float4*)RC;
    for (int i = tid; i < 1024; i += 256) { z1[i] = z; z2[i] = z; z3[i] = z; }
  }

  // ---- GEMM phase (global reads only) ----
  const f32x4 zf = {0.f, 0.f, 0.f, 0.f};
  f32x4 acc[4][6];
#pragma unroll
  for (int mi = 0; mi < 4; ++mi)
#pragma unroll
    for (int nt = 0; nt < 6; ++nt) acc[mi][nt] = zf;

#pragma unroll
  for (int ks = 0; ks < 8; ++ks) {
    int k0 = ks * 32 + lk;
    short8v bfr[6];
#pragma unroll
    for (int nt = 0; nt < 6; ++nt) {
      int orow = (nt >> 1) * 248 + h * 31 + (nt & 1) * 16 + lr;
      bfr[nt] = *(const short8v*)(wbf + (size_t)orow * 256 + k0);
    }
#pragma unroll
    for (int mi = 0; mi < 4; ++mi) {
      if (mi < mcount) {
        short8v a = *(const short8v*)(xb + (size_t)((mstart + mi) * 16 + lr) * 256 + k0);
#pragma unroll
        for (int nt = 0; nt < 6; ++nt)
          acc[mi][nt] = __builtin_amdgcn_mfma_f32_16x16x32_bf16(a, bfr[nt], acc[mi][nt], 0, 0, 0);
      }
    }
  }
  __syncthreads();
  // ---- scatter D-frags into swizzled Qs(RA)/Ks(RB)/Vt(RC) ----
#pragma unroll
  for (int mi = 0; mi < 4; ++mi) {
    if (mi < mcount) {
      int p = (mstart + mi) * 4 + (l >> 4);
      if (p < P_) {
#pragma unroll
        for (int nt = 0; nt < 6; ++nt) {
          int d = (nt & 1) * 16 + lr;
          if (d < D_) {
            int wi = nt >> 1;
            float bo = bias[wi * C_ + h * D_ + d];
            f32x4 av = acc[mi][nt];
            if (wi == 2) {
#pragma unroll
              for (int r = 0; r < 4; ++r) {
                int dh = d * 4 + r;
                *(unsigned short*)((char*)RC + ((dh * 128 + p * 2) ^ ((dh & 7) << 4))) = f2bf(av[0] + bo);
                av = __builtin_shufflevector(av, av, 1, 2, 3, 0);
              }
            } else if (wi == 0) {
              ushort4 pk;
              pk.x = f2bf((av[0] + bo) * scale); pk.y = f2bf((av[1] + bo) * scale);
              pk.z = f2bf((av[2] + bo) * scale); pk.w = f2bf((av[3] + bo) * scale);
              *(ushort4*)((char*)RA + ((p * 256 + d * 8) ^ ((p & 7) << 4))) = pk;
            } else {
              ushort4 pk;
              pk.x = f2bf(av[0] + bo); pk.y = f2bf(av[1] + bo);
              pk.z = f2bf(av[2] + bo); pk.w = f2bf(av[3] + bo);
              *(ushort4*)((char*)RB + ((p * 256 + d * 8) ^ ((p & 7) << 4))) = pk;
            }
          }
        }
      }
    }
  }
  __syncthreads();

  // ---- QK^T + rel-bias MFMA ----
  const int arow = 16 * w + lr;
  const int prow0 = 16 * w + (l >> 4) * 4;

  f32x4 accS[4]; f32x4 accR[7];
#pragma unroll
  for (int n = 0; n < 4; ++n) accS[n] = zf;
#pragma unroll
  for (int n = 0; n < 7; ++n) accR[n] = zf;

#pragma unroll
  for (int ks = 0; ks < 4; ++ks) {
    int k0 = ks * 32 + lk;
    short8v a = *(const short8v*)((const char*)RA + ((arow * 256 + 2 * k0) ^ ((arow & 7) << 4)));
#pragma unroll
    for (int n = 0; n < 4; ++n) {
      int brow = 16 * n + lr;
      short8v bb = *(const short8v*)((const char*)RB + ((brow * 256 + 2 * k0) ^ ((brow & 7) << 4)));
      accS[n] = __builtin_amdgcn_mfma_f32_16x16x32_bf16(a, bb, accS[n], 0, 0, 0);
    }
#pragma unroll
    for (int n = 0; n < 7; ++n) {
      int rrow = 16 * n + lr;
      short8v bb = *(const short8v*)(relp + rrow * 128 + k0);
      accR[n] = __builtin_amdgcn_mfma_f32_16x16x32_bf16(a, bb, accR[n], 0, 0, 0);
    }
  }
  __syncthreads();   // all waves done reading RB before bias_s overwrites it

  // ---- diagonal-shifted bias store: bias_s[p][j] = brel[p][49+j-p] ----
  unsigned short* bias_s = RB;
#pragma unroll
  for (int n = 0; n < 7; ++n)
#pragma unroll
    for (int r = 0; r < 4; ++r) {
      int p = prow0 + r;
      int j = 16 * n + lr - 49 + p;
      if (p < P_ && j >= 0 && j < P_)
        bias_s[p * 64 + j] = f2bf(accR[n][r]);
    }
  __syncthreads();

  // ---- softmax (reads bias_s=RB, writes Ps into RA) ----
  float sv[4][4];
#pragma unroll
  for (int n = 0; n < 4; ++n)
#pragma unroll
    for (int r = 0; r < 4; ++r) {
      int p = prow0 + r, j = 16 * n + lr;
      if (p < P_ && j < P_)
        sv[n][r] = accS[n][r] + bf2f(bias_s[p * 64 + j]);
      else
        sv[n][r] = -1e30f;
    }
#pragma unroll
  for (int r = 0; r < 4; ++r) {
    float mm = fmaxf(fmaxf(sv[0][r], sv[1][r]), fmaxf(sv[2][r], sv[3][r]));
    mm = fmaxf(mm, __shfl_xor(mm, 1));
    mm = fmaxf(mm, __shfl_xor(mm, 2));
    mm = fmaxf(mm, __shfl_xor(mm, 4));
    mm = fmaxf(mm, __shfl_xor(mm, 8));
    float ss = 0.f;
#pragma unroll
    for (int n = 0; n < 4; ++n) { float e = __expf(sv[n][r] - mm); sv[n][r] = e; ss += e; }
    ss += __shfl_xor(ss, 1); ss += __shfl_xor(ss, 2);
    ss += __shfl_xor(ss, 4); ss += __shfl_xor(ss, 8);
    float inv = 1.f / ss;
#pragma unroll
    for (int n = 0; n < 4; ++n) sv[n][r] *= inv;
  }
#pragma unroll
  for (int n = 0; n < 4; ++n)
#pragma unroll
    for (int r = 0; r < 4; ++r) {
      int p = prow0 + r, j = 16 * n + lr;
      *(unsigned short*)((char*)RA + ((p * 128 + 2 * j) ^ ((p & 7) << 4))) = f2bf(sv[n][r]);
    }
  __syncthreads();

  // ---- PV (reads Ps=RA, Vt=RC) ----
  f32x4 accO[8];
#pragma unroll
  for (int n = 0; n < 8; ++n) accO[n] = zf;
#pragma unroll
  for (int ks = 0; ks < 2; ++ks) {
    int j0 = ks * 32 + lk;
    short8v a = *(const short8v*)((const char*)RA + ((arow * 128 + 2 * j0) ^ ((arow & 7) << 4)));
#pragma unroll
    for (int n = 0; n < 8; ++n) {
      int vrow = 16 * n + lr;
      short8v bb = *(const short8v*)((const char*)RC + ((vrow * 128 + 2 * j0) ^ ((vrow & 7) << 4)));
      accO[n] = __builtin_amdgcn_mfma_f32_16x16x32_bf16(a, bb, accO[n], 0, 0, 0);
    }
  }
  // ---- epilogue: p1T write + BN1 partial stats ----
  float psum[8], psq[8];
#pragma unroll
  for (int n = 0; n < 8; ++n) { psum[n] = 0.f; psq[n] = 0.f; }
#pragma unroll
  for (int n = 0; n < 8; ++n) {
    int dh = 16 * n + lr;
    if (dh < DH_) {
      int c = h * D_ + (dh >> 2), t = dh & 3;
#pragma unroll
      for (int r = 0; r < 4; ++r) {
        int p = prow0 + r;
        if (p < P_) {
          float val = accO[n][r] + x[(((size_t)b * C_ + c) * P_ + p) * T_ + t];
          p1T[((size_t)b * 50 + p) * 1024 + h * DH_ + dh] = f2bf(val);
          psum[n] += val;
          psq[n] += val * val;
        }
      }
    }
  }
#pragma unroll
  for (int n = 0; n < 8; ++n) {
    psum[n] += __shfl_xor(psum[n], 1);  psq[n] += __shfl_xor(psq[n], 1);
    psum[n] += __shfl_xor(psum[n], 2);  psq[n] += __shfl_xor(psq[n], 2);
    psum[n] += __shfl_xor(psum[n], 16); psq[n] += __shfl_xor(psq[n], 16);
    psum[n] += __shfl_xor(psum[n], 32); psq[n] += __shfl_xor(psq[n], 32);
  }
  float* fs = (float*)RB;   // bias_s dead (post-softmax sync passed); PV touches RA/RC only
  if ((l & 3) == 0 && l < 16) {
    int g2 = l >> 2;
#pragma unroll
    for (int n = 0; n < 8; ++n) {
      int d = 4 * n + g2;
      if (d < D_) { fs[w * 32 + d] = psum[n]; fs[128 + w * 32 + d] = psq[n]; }
    }
  }
  __syncthreads();
  if (tid < D_) {
    float s = fs[tid] + fs[32 + tid] + fs[64 + tid] + fs[96 + tid];
    float s2 = fs[128 + tid] + fs[160 + tid] + fs[192 + tid] + fs[224 + tid];
    partial1[((size_t)b * 8 + h) * 62 + tid] = s;
    partial1[((size_t)b * 8 + h) * 62 + 31 + tid] = s2;
  }
  if (h == 7) {   // const column 992 (=1.0) and zero cols 993..1023 of p1T
    for (int u = tid; u < 400; u += 256) {
      int p = u >> 3, g3 = u & 7;
      ushort4 vz = make_ushort4(0, 0, 0, 0);
      if (g3 == 0) vz.x = 0x3F80;
      *(ushort4*)(p1T + ((size_t)b * 50 + p) * 1024 + 992 + g3 * 4) = vz;
    }
  }
}

// BN1 finalize: 248 blocks, thread = b; sums partial1 over b.
__global__ __launch_bounds__(256) void bnfin1_kernel(
    const float* __restrict__ partial1, const float* __restrict__ g,
    const float* __restrict__ be, float* __restrict__ a, float* __restrict__ bs) {
  const int c = blockIdx.x;
  const int h = c / D_, d = c - h * D_;
  const int tid = threadIdx.x;
  const float* pp = partial1 + ((size_t)tid * 8 + h) * 62;
  float s = pp[d], s2 = pp[31 + d];
#pragma unroll
  for (int off = 1; off <= 32; off <<= 1) {
    s += __shfl_xor(s, off);
    s2 += __shfl_xor(s2, off);
  }
  __shared__ float r1[4], r2[4];
  if ((tid & 63) == 0) { r1[tid >> 6] = s; r2[tid >> 6] = s2; }
  __syncthreads();
  if (tid == 0) {
    s = r1[0] + r1[1] + r1[2] + r1[3];
    s2 = r2[0] + r2[1] + r2[2] + r2[3];
    const float inv = 1.f / (float)(B_ * PT_);
    float m = s * inv;
    float var = s2 * inv - m * m;
    float ai = g[c] * rsqrtf(var + 1e-5f);
    a[c] = ai;
    bs[c] = be[c] - m * ai;
  }
}

// Parallel BN stats stage 1: grid (nch, 8); block = 32 b x 8 chunk-threads.
__global__ __launch_bounds__(256) void bnstat_part_kernel(
    const float* __restrict__ t, float* __restrict__ part, int nch) {
  const int c = blockIdx.x, g = blockIdx.y;
  const int tid = threadIdx.x;
  const int bsl = tid >> 3, k = tid & 7;
  const int b = g * 32 + bsl;
  const float* base = t + ((size_t)b * nch + c) * PT_;
  float s = 0.f, s2 = 0.f;
  for (int j = k; j < 50; j += 8) {
    float4 v = *(const float4*)(base + j * 4);
    s += v.x + v.y + v.z + v.w;
    s2 += v.x * v.x + v.y * v.y + v.z * v.z + v.w * v.w;
  }
#pragma unroll
  for (int off = 1; off <= 32; off <<= 1) {
    s += __shfl_xor(s, off);
    s2 += __shfl_xor(s2, off);
  }
  __shared__ float r1[4], r2[4];
  if ((tid & 63) == 0) { r1[tid >> 6] = s; r2[tid >> 6] = s2; }
  __syncthreads();
  if (tid == 0) {
    s = r1[0] + r1[1] + r1[2] + r1[3];
    s2 = r2[0] + r2[1] + r2[2] + r2[3];
    part[((size_t)c * 8 + g) * 2] = s;
    part[((size_t)c * 8 + g) * 2 + 1] = s2;
  }
}

// BN stats stage 2 (generic finalize)
__global__ __launch_bounds__(256) void bnfin_kernel(
    const float* __restrict__ part, const float* __restrict__ g,
    const float* __restrict__ be, float* __restrict__ a, float* __restrict__ bs, int nch) {
  int c = threadIdx.x;
  if (c < nch) {
    float s = 0.f, s2 = 0.f;
#pragma unroll
    for (int gg = 0; gg < 8; ++gg) {
      s += part[((size_t)c * 8 + gg) * 2];
      s2 += part[((size_t)c * 8 + gg) * 2 + 1];
    }
    const float inv = 1.f / (float)(B_ * PT_);
    float m = s * inv;
    float var = s2 * inv - m * m;
    float ai = g[c] * rsqrtf(var + 1e-5f);
    a[c] = ai;
    bs[c] = be[c] - m * ai;
  }
}

// K4b: build Wbig bf16 [64 n=(f,t)][1024 K=(c,t')+const] folding conv taps, a1, b1, bc
__global__ __launch_bounds__(256) void wcfe_kernel(
    const float* __restrict__ w1, const float* __restrict__ bc1,
    const float* __restrict__ w2, const float* __restrict__ bc2,
    const float* __restrict__ a1, const float* __restrict__ b1,
    unsigned short* __restrict__ Wbig) {
  const int n = blockIdx.x;
  const int f = n >> 2, t = n & 3;
  const int tid = threadIdx.x;
  __shared__ float red[256];
  float partial = 0.f;
  if (tid < C_) {
    int c = tid;
    float tv[4];
    float tsum = 0.f;
#pragma unroll
    for (int tp = 0; tp < 4; ++tp) {
      int dt = tp - t;
      float v = 0.f;
      if (f < 8) { if (dt >= -1 && dt <= 1) v = w1[(f * C_ + c) * 3 + dt + 1]; }
      else       { if (dt >= -2 && dt <= 2) v = w2[((f - 8) * C_ + c) * 5 + dt + 2]; }
      tv[tp] = v; tsum += v;
    }
    float ac = a1[c];
#pragma unroll
    for (int tp = 0; tp < 4; ++tp)
      Wbig[n * 1024 + c * 4 + tp] = f2bf(ac * tv[tp]);
    partial = b1[c] * tsum;
  } else {
#pragma unroll
    for (int tp = 0; tp < 4; ++tp) {
      int col = tid * 4 + tp;
      if (col > 992 && col < 1024) Wbig[n * 1024 + col] = 0;
    }
  }
  red[tid] = partial;
  __syncthreads();
  for (int s = 128; s > 0; s >>= 1) {
    if (tid < s) red[tid] += red[tid + s];
    __syncthreads();
  }
  if (tid == 0) {
    float bias = (f < 8) ? bc1[f] : bc2[f - 8];
    Wbig[n * 1024 + 992] = f2bf(bias + red[0]);
  }
}

// K4c: MFMA GEMM: y16[m=(b,p), n=(f,t)] = p1T[m] . Wbig[n].  M=12800, N=64, K=1024.
__global__ __launch_bounds__(256) void cfe12g_kernel(
    const unsigned short* __restrict__ p1T, const unsigned short* __restrict__ Wbig,
    float* __restrict__ y16) {
  const int tid = threadIdx.x;
  const int w = tid >> 6, l = tid & 63;
  const int lr = l & 15, lk = (l >> 4) * 8;
  const int m0 = blockIdx.x * 32;
  const f32x4 zf = {0.f, 0.f, 0.f, 0.f};
  f32x4 acc0 = zf, acc1 = zf;
  const unsigned short* wrow = Wbig + (size_t)(w * 16 + lr) * 1024;
#pragma unroll
  for (int ks = 0; ks < 32; ++ks) {
    int k0 = ks * 32 + lk;
    short8v bfr = *(const short8v*)(wrow + k0);
    short8v a0 = *(const short8v*)(p1T + (size_t)(m0 + lr) * 1024 + k0);
    short8v a1v = *(const short8v*)(p1T + (size_t)(m0 + 16 + lr) * 1024 + k0);
    acc0 = __builtin_amdgcn_mfma_f32_16x16x32_bf16(a0, bfr, acc0, 0, 0, 0);
    acc1 = __builtin_amdgcn_mfma_f32_16x16x32_bf16(a1v, bfr, acc1, 0, 0, 0);
  }
  const int n = w * 16 + lr, f = n >> 2, tt = n & 3;
#pragma unroll
  for (int mt = 0; mt < 2; ++mt) {
    f32x4 av = (mt == 0) ? acc0 : acc1;
#pragma unroll
    for (int r = 0; r < 4; ++r) {
      int m = m0 + mt * 16 + (l >> 4) * 4 + r;
      int b = m / 50, p = m - (m / 50) * 50;
      y16[((size_t)b * 16 + f) * PT_ + p * 4 + tt] = av[r];
    }
  }
}

// K6: ELU(BN_cfe(y16)) -> conv3 (16->248) + BN1-residual (from p1T bf16) -> pre2
__global__ __launch_bounds__(256) void cfe3_kernel(
    const float* __restrict__ y16, const float* __restrict__ ac, const float* __restrict__ bcf,
    const float* __restrict__ w3, const float* __restrict__ bc3,
    const unsigned short* __restrict__ p1T, const float* __restrict__ a1, const float* __restrict__ b1,
    float* __restrict__ pre2) {
  const int b = blockIdx.x;
  const int tid = threadIdx.x;
  __shared__ float zs[16][PT_];
  __shared__ float w3s[C_][16];
  for (int i = tid; i < C_ * 16; i += 256) w3s[i >> 4][i & 15] = w3[i];
  for (int e = tid; e < 16 * PT_; e += 256) {
    int f = e / PT_, pt = e - f * PT_;
    float v = y16[((size_t)b * 16 + f) * PT_ + pt] * ac[f] + bcf[f];
    zs[f][pt] = (v > 0.f) ? v : (__expf(v) - 1.f);
  }
  __syncthreads();
  for (int e = tid; e < C_ * P_; e += 256) {
    int c = e / P_, p = e - (e / P_) * P_;
    float b3 = bc3[c];
    float4 o = make_float4(b3, b3, b3, b3);
#pragma unroll
    for (int f = 0; f < 16; ++f) {
      float wv = w3s[c][f];
      float4 z = *(const float4*)&zs[f][p * 4];
      o.x += wv * z.x; o.y += wv * z.y; o.z += wv * z.z; o.w += wv * z.w;
    }
    ushort4 xr = *(const ushort4*)(p1T + ((size_t)(b * 50 + p)) * 1024 + c * 4);
    float a1c = a1[c], b1c = b1[c];
    o.x += bf2f(xr.x) * a1c + b1c;
    o.y += bf2f(xr.y) * a1c + b1c;
    o.z += bf2f(xr.z) * a1c + b1c;
    o.w += bf2f(xr.w) * a1c + b1c;
    size_t idx = (((size_t)b * C_ + c) * P_ + p) * T_;
    *(float4*)(pre2 + idx) = o;
  }
}

// K8: apply BN2 -> out
__global__ __launch_bounds__(256) void bnapply_kernel(
    const float* __restrict__ pre2, const float* __restrict__ a, const float* __restrict__ bs,
    float* __restrict__ out) {
  int i = blockIdx.x * 256 + threadIdx.x;
  if (i < (B_ * C_ * PT_) / 4) {
    int row = (i * 4) / PT_;
    int c = row % C_;
    float4 v = *(const float4*)(pre2 + (size_t)i * 4);
    float ai = a[c], bi = bs[c];
    float4 o = make_float4(v.x * ai + bi, v.y * ai + bi, v.z * ai + bi, v.w * ai + bi);
    *(float4*)(out + (size_t)i * 4) = o;
  }
}

extern "C" void kernel_launch(void* const* d_in, const int* in_sizes, int n_in,
                              void* d_out, int out_size, void* d_ws, size_t ws_size,
                              hipStream_t stream) {
  const float* x        = (const float*)d_in[0];
  const float* w_qkv    = (const float*)d_in[1];
  const float* b_qkv    = (const float*)d_in[2];
  const float* rel      = (const float*)d_in[3];
  const float* g1       = (const float*)d_in[4];
  const float* beta1    = (const float*)d_in[5];
  const float* w_c1     = (const float*)d_in[6];
  const float* bc1      = (const float*)d_in[7];
  const float* w_c2     = (const float*)d_in[8];
  const float* bc2      = (const float*)d_in[9];
  const float* g_cfe    = (const float*)d_in[10];
  const float* beta_cfe = (const float*)d_in[11];
  const float* w_c3     = (const float*)d_in[12];
  const float* bc3      = (const float*)d_in[13];
  const float* g2       = (const float*)d_in[14];
  const float* beta2    = (const float*)d_in[15];
  float* out = (float*)d_out;
  char* ws = (char*)d_ws;

  // ws layout (bytes):
  //   0          xT bf16 (27,262,976)   [dead after fused_qa]
  //   27262976   wbf bf16 (393,216)     [dead after fused_qa]
  //   27656192   p1T bf16 (26,214,400)  [fused_qa writes; cfe12g + cfe3 read]
  //   53870592   part2 f32 (15,872)
  //   53886464   partY f32 (1,024)
  //   76185600   pre2 f32 (50,790,400)
  //   126976000  y16 f32 (3,276,800); partial1 f32 (507,904) aliases this region
  //              (fused_qa writes partial1 -> bnfin1 reads -> cfe12g overwrites with y16)
  //   130252800  relp bf16 (28,672)
  //   130281472  Wbig bf16 (131,072)
  //   130412544  st f32 (a1,b1,acf,bcf,a2,b2)
  unsigned short* xT    = (unsigned short*)(ws);
  unsigned short* wbf   = (unsigned short*)(ws + 27262976);
  unsigned short* p1T   = (unsigned short*)(ws + 27656192);
  float* part2          = (float*)(ws + 53870592);
  float* partY          = (float*)(ws + 53886464);
  float* pre2           = (float*)(ws + 76185600);
  float* y16            = (float*)(ws + 126976000);
  float* partial1       = (float*)(ws + 126976000);
  unsigned short* relp  = (unsigned short*)(ws + 130252800);
  unsigned short* Wbig  = (unsigned short*)(ws + 130281472);
  float* st             = (float*)(ws + 130412544);
  float* a1 = st, *b1 = st + 256, *acf = st + 512, *bcf = st + 544, *a2 = st + 576, *b2 = st + 832;

  relcvt_kernel<<<56, 256, 0, stream>>>(rel, relp);
  wcvt_kernel<<<192, 256, 0, stream>>>(w_qkv, wbf);
  xt_kernel<<<dim3(16, 256), 256, 0, stream>>>(x, xT);
  fused_qa_kernel<<<2048, 256, 0, stream>>>(xT, wbf, b_qkv, relp, x, p1T, partial1);
  bnfin1_kernel<<<248, 256, 0, stream>>>(partial1, g1, beta1, a1, b1);
  wcfe_kernel<<<64, 256, 0, stream>>>(w_c1, bc1, w_c2, bc2, a1, b1, Wbig);
  cfe12g_kernel<<<400, 256, 0, stream>>>(p1T, Wbig, y16);
  bnstat_part_kernel<<<dim3(16, 8), 256, 0, stream>>>(y16, partY, 16);
  bnfin_kernel<<<1, 256, 0, stream>>>(partY, g_cfe, beta_cfe, acf, bcf, 16);
  cfe3_kernel<<<256, 256, 0, stream>>>(y16, acf, bcf, w_c3, bc3, p1T, a1, b1, pre2);
  bnstat_part_kernel<<<dim3(248, 8), 256, 0, stream>>>(pre2, part2, 248);
  bnfin_kernel<<<1, 256, 0, stream>>>(part2, g2, beta2, a2, b2, 248);
  bnapply_kernel<<<12400, 256, 0, stream>>>(pre2, a2, b2, out);
}

// Round 13
// 349.342 us; speedup vs baseline: 1.2838x; 1.0506x over previous
//
#include <hip/hip_runtime.h>

#define B_ 256
#define C_ 248
#define P_ 50
#define T_ 4
#define H_ 8
#define D_ 31
#define DH_ 124
#define PT_ 200
#define O3_ 744

typedef __attribute__((ext_vector_type(8))) short short8v;
typedef __attribute__((ext_vector_type(4))) float f32x4;

__device__ __forceinline__ float bf2f(unsigned short u) {
  union { unsigned int i; float f; } v; v.i = ((unsigned int)u) << 16; return v.f;
}
__device__ __forceinline__ unsigned short f2bf(float f) {
  union { float f; unsigned int i; } v; v.f = f;
  unsigned int r = v.i + 0x7fffu + ((v.i >> 16) & 1u);
  return (unsigned short)(r >> 16);
}

// K0: rel_emb fp32 -> bf16, zero-padded to [112][128]
__global__ void relcvt_kernel(const float* __restrict__ rel, unsigned short* __restrict__ out) {
  int i = blockIdx.x * 256 + threadIdx.x;
  if (i < 112 * 128) {
    int r = i >> 7, k = i & 127;
    out[i] = (r < 99 && k < DH_) ? f2bf(rel[r * DH_ + k]) : (unsigned short)0;
  }
}

// K0b: w_qkv fp32 [744][248] -> bf16 zero-padded [768][256]
__global__ void wcvt_kernel(const float* __restrict__ w, unsigned short* __restrict__ wbf) {
  int i = blockIdx.x * 256 + threadIdx.x;
  if (i < 768 * 64) {
    int o = i >> 6, c = (i & 63) * 4;
    ushort4 val = make_ushort4(0, 0, 0, 0);
    if (o < O3_ && c < C_) {
      float4 wv = *(const float4*)(w + (size_t)o * C_ + c);
      val.x = f2bf(wv.x); val.y = f2bf(wv.y); val.z = f2bf(wv.z); val.w = f2bf(wv.w);
    }
    *(ushort4*)(wbf + (size_t)o * 256 + c) = val;
  }
}

// K0c: x fp32 [b][248][200] -> xT bf16 [b][208][256] (pt-major, zero-padded)
__global__ __launch_bounds__(256) void xt_kernel(const float* __restrict__ x,
                                                 unsigned short* __restrict__ xT) {
  __shared__ float xs[64 * 65];
  const int tid = threadIdx.x;
  const int pt0 = (blockIdx.x & 3) * 64;
  const int c0 = (blockIdx.x >> 2) * 64;
  const int b = blockIdx.y;
#pragma unroll
  for (int pass = 0; pass < 4; ++pass) {
    int row = pass * 16 + (tid >> 4);
    int ptl4 = (tid & 15) * 4;
    int c = c0 + row, pt = pt0 + ptl4;
    float4 v = make_float4(0.f, 0.f, 0.f, 0.f);
    if (c < C_) {
      const float* src = x + ((size_t)b * C_ + c) * PT_ + pt;
      if (pt + 3 < PT_) v = *(const float4*)src;
      else {
        if (pt + 0 < PT_) v.x = src[0];
        if (pt + 1 < PT_) v.y = src[1];
        if (pt + 2 < PT_) v.z = src[2];
        if (pt + 3 < PT_) v.w = src[3];
      }
    }
    xs[row * 65 + ptl4 + 0] = v.x; xs[row * 65 + ptl4 + 1] = v.y;
    xs[row * 65 + ptl4 + 2] = v.z; xs[row * 65 + ptl4 + 3] = v.w;
  }
  __syncthreads();
#pragma unroll
  for (int pass = 0; pass < 4; ++pass) {
    int ptl = pass * 16 + (tid >> 4);
    int cl4 = (tid & 15) * 4;
    int pt = pt0 + ptl;
    if (pt < 208) {
      ushort4 pk;
      pk.x = f2bf(xs[(cl4 + 0) * 65 + ptl]);
      pk.y = f2bf(xs[(cl4 + 1) * 65 + ptl]);
      pk.z = f2bf(xs[(cl4 + 2) * 65 + ptl]);
      pk.w = f2bf(xs[(cl4 + 3) * 65 + ptl]);
      *(ushort4*)(xT + ((size_t)b * 208 + pt) * 256 + c0 + cl4) = pk;
    }
  }
}

// K1: FUSED qkv-GEMM + attention per (b,h). LDS 61.4KB time-shared:
//   RA: Qs -> Ps; RB: Ks -> bias_s -> stats; RC: Vt; RD: x-slice (residual, bf16)
// Epilogue writes p1T bf16 (pre1 never in f32) + BN1 partial stats.
__global__ __launch_bounds__(256) void fused_qa_kernel(
    const unsigned short* __restrict__ xT, const unsigned short* __restrict__ wbf,
    const float* __restrict__ bias, const unsigned short* __restrict__ relp,
    unsigned short* __restrict__ p1T, float* __restrict__ partial1) {
  __shared__ __align__(16) unsigned short RA[64 * 128];
  __shared__ __align__(16) unsigned short RB[64 * 128];
  __shared__ __align__(16) unsigned short RC[128 * 64];
  __shared__ __align__(16) unsigned short RD[208 * 32];
  const int tid = threadIdx.x;
  const int xcd = blockIdx.x & 7, slot = blockIdx.x >> 3;
  const int b = xcd * 32 + (slot >> 3), h = slot & 7;
  const unsigned short* xb = xT + (size_t)b * 208 * 256;
  const int w = tid >> 6, l = tid & 63;
  const int lr = l & 15, lk = (l >> 4) * 8;
  const int mstart = (w == 0) ? 0 : (1 + 3 * w);   // {0,4,7,10}
  const int mcount = (w == 0) ? 4 : 3;
  const float scale = 0.17960530202677491f;

  {
    float4 z = make_float4(0.f, 0.f, 0.f, 0.f);
    float4* z1 = (float4*)RA; float4* z2 = (float4*)RB; float4* z3 = (float4*)RC;
    for (int i = tid; i < 1024; i += 256) { z1[i] = z; z2[i] = z; z3[i] = z; }
  }
  // stage x residual slice: RD[pt][d] = xT[b][pt][h*31+d], coalesced (L2-hot)
  for (int i = tid; i < 208 * 31; i += 256) {
    int row = i / 31, cc = i - (i / 31) * 31;
    RD[row * 32 + cc] = xb[row * 256 + h * 31 + cc];
  }

  // ---- GEMM phase (global reads only) ----
  const f32x4 zf = {0.f, 0.f, 0.f, 0.f};
  f32x4 acc[4][6];
#pragma unroll
  for (int mi = 0; mi < 4; ++mi)
#pragma unroll
    for (int nt = 0; nt < 6; ++nt) acc[mi][nt] = zf;

#pragma unroll
  for (int ks = 0; ks < 8; ++ks) {
    int k0 = ks * 32 + lk;
    short8v bfr[6];
#pragma unroll
    for (int nt = 0; nt < 6; ++nt) {
      int orow = (nt >> 1) * 248 + h * 31 + (nt & 1) * 16 + lr;
      bfr[nt] = *(const short8v*)(wbf + (size_t)orow * 256 + k0);
    }
#pragma unroll
    for (int mi = 0; mi < 4; ++mi) {
      if (mi < mcount) {
        short8v a = *(const short8v*)(xb + (size_t)((mstart + mi) * 16 + lr) * 256 + k0);
#pragma unroll
        for (int nt = 0; nt < 6; ++nt)
          acc[mi][nt] = __builtin_amdgcn_mfma_f32_16x16x32_bf16(a, bfr[nt], acc[mi][nt], 0, 0, 0);
      }
    }
  }
  __syncthreads();
  // ---- scatter D-frags into swizzled Qs(RA)/Ks(RB)/Vt(RC) ----
#pragma unroll
  for (int mi = 0; mi < 4; ++mi) {
    if (mi < mcount) {
      int p = (mstart + mi) * 4 + (l >> 4);
      if (p < P_) {
#pragma unroll
        for (int nt = 0; nt < 6; ++nt) {
          int d = (nt & 1) * 16 + lr;
          if (d < D_) {
            int wi = nt >> 1;
            float bo = bias[wi * C_ + h * D_ + d];
            f32x4 av = acc[mi][nt];
            if (wi == 2) {
#pragma unroll
              for (int r = 0; r < 4; ++r) {
                int dh = d * 4 + r;
                *(unsigned short*)((char*)RC + ((dh * 128 + p * 2) ^ ((dh & 7) << 4))) = f2bf(av[0] + bo);
                av = __builtin_shufflevector(av, av, 1, 2, 3, 0);
              }
            } else if (wi == 0) {
              ushort4 pk;
              pk.x = f2bf((av[0] + bo) * scale); pk.y = f2bf((av[1] + bo) * scale);
              pk.z = f2bf((av[2] + bo) * scale); pk.w = f2bf((av[3] + bo) * scale);
              *(ushort4*)((char*)RA + ((p * 256 + d * 8) ^ ((p & 7) << 4))) = pk;
            } else {
              ushort4 pk;
              pk.x = f2bf(av[0] + bo); pk.y = f2bf(av[1] + bo);
              pk.z = f2bf(av[2] + bo); pk.w = f2bf(av[3] + bo);
              *(ushort4*)((char*)RB + ((p * 256 + d * 8) ^ ((p & 7) << 4))) = pk;
            }
          }
        }
      }
    }
  }
  __syncthreads();

  // ---- QK^T + rel-bias MFMA ----
  const int arow = 16 * w + lr;
  const int prow0 = 16 * w + (l >> 4) * 4;

  f32x4 accS[4]; f32x4 accR[7];
#pragma unroll
  for (int n = 0; n < 4; ++n) accS[n] = zf;
#pragma unroll
  for (int n = 0; n < 7; ++n) accR[n] = zf;

#pragma unroll
  for (int ks = 0; ks < 4; ++ks) {
    int k0 = ks * 32 + lk;
    short8v a = *(const short8v*)((const char*)RA + ((arow * 256 + 2 * k0) ^ ((arow & 7) << 4)));
#pragma unroll
    for (int n = 0; n < 4; ++n) {
      int brow = 16 * n + lr;
      short8v bb = *(const short8v*)((const char*)RB + ((brow * 256 + 2 * k0) ^ ((brow & 7) << 4)));
      accS[n] = __builtin_amdgcn_mfma_f32_16x16x32_bf16(a, bb, accS[n], 0, 0, 0);
    }
#pragma unroll
    for (int n = 0; n < 7; ++n) {
      int rrow = 16 * n + lr;
      short8v bb = *(const short8v*)(relp + rrow * 128 + k0);
      accR[n] = __builtin_amdgcn_mfma_f32_16x16x32_bf16(a, bb, accR[n], 0, 0, 0);
    }
  }
  __syncthreads();   // all waves done reading RB before bias_s overwrites it

  // ---- diagonal-shifted bias store: bias_s[p][j] = brel[p][49+j-p] ----
  unsigned short* bias_s = RB;
#pragma unroll
  for (int n = 0; n < 7; ++n)
#pragma unroll
    for (int r = 0; r < 4; ++r) {
      int p = prow0 + r;
      int j = 16 * n + lr - 49 + p;
      if (p < P_ && j >= 0 && j < P_)
        bias_s[p * 64 + j] = f2bf(accR[n][r]);
    }
  __syncthreads();

  // ---- softmax (reads bias_s=RB, writes Ps into RA) ----
  float sv[4][4];
#pragma unroll
  for (int n = 0; n < 4; ++n)
#pragma unroll
    for (int r = 0; r < 4; ++r) {
      int p = prow0 + r, j = 16 * n + lr;
      if (p < P_ && j < P_)
        sv[n][r] = accS[n][r] + bf2f(bias_s[p * 64 + j]);
      else
        sv[n][r] = -1e30f;
    }
#pragma unroll
  for (int r = 0; r < 4; ++r) {
    float mm = fmaxf(fmaxf(sv[0][r], sv[1][r]), fmaxf(sv[2][r], sv[3][r]));
    mm = fmaxf(mm, __shfl_xor(mm, 1));
    mm = fmaxf(mm, __shfl_xor(mm, 2));
    mm = fmaxf(mm, __shfl_xor(mm, 4));
    mm = fmaxf(mm, __shfl_xor(mm, 8));
    float ss = 0.f;
#pragma unroll
    for (int n = 0; n < 4; ++n) { float e = __expf(sv[n][r] - mm); sv[n][r] = e; ss += e; }
    ss += __shfl_xor(ss, 1); ss += __shfl_xor(ss, 2);
    ss += __shfl_xor(ss, 4); ss += __shfl_xor(ss, 8);
    float inv = 1.f / ss;
#pragma unroll
    for (int n = 0; n < 4; ++n) sv[n][r] *= inv;
  }
#pragma unroll
  for (int n = 0; n < 4; ++n)
#pragma unroll
    for (int r = 0; r < 4; ++r) {
      int p = prow0 + r, j = 16 * n + lr;
      *(unsigned short*)((char*)RA + ((p * 128 + 2 * j) ^ ((p & 7) << 4))) = f2bf(sv[n][r]);
    }
  __syncthreads();

  // ---- PV (reads Ps=RA, Vt=RC) ----
  f32x4 accO[8];
#pragma unroll
  for (int n = 0; n < 8; ++n) accO[n] = zf;
#pragma unroll
  for (int ks = 0; ks < 2; ++ks) {
    int j0 = ks * 32 + lk;
    short8v a = *(const short8v*)((const char*)RA + ((arow * 128 + 2 * j0) ^ ((arow & 7) << 4)));
#pragma unroll
    for (int n = 0; n < 8; ++n) {
      int vrow = 16 * n + lr;
      short8v bb = *(const short8v*)((const char*)RC + ((vrow * 128 + 2 * j0) ^ ((vrow & 7) << 4)));
      accO[n] = __builtin_amdgcn_mfma_f32_16x16x32_bf16(a, bb, accO[n], 0, 0, 0);
    }
  }
  // ---- epilogue: p1T write (residual from RD) + BN1 partial stats ----
  float psum[8], psq[8];
#pragma unroll
  for (int n = 0; n < 8; ++n) { psum[n] = 0.f; psq[n] = 0.f; }
#pragma unroll
  for (int n = 0; n < 8; ++n) {
    int dh = 16 * n + lr;
    if (dh < DH_) {
      int d = dh >> 2, t = dh & 3;
#pragma unroll
      for (int r = 0; r < 4; ++r) {
        int p = prow0 + r;
        if (p < P_) {
          float val = accO[n][r] + bf2f(RD[(4 * p + t) * 32 + d]);
          p1T[((size_t)b * 50 + p) * 1024 + h * DH_ + dh] = f2bf(val);
          psum[n] += val;
          psq[n] += val * val;
        }
      }
    }
  }
#pragma unroll
  for (int n = 0; n < 8; ++n) {
    psum[n] += __shfl_xor(psum[n], 1);  psq[n] += __shfl_xor(psq[n], 1);
    psum[n] += __shfl_xor(psum[n], 2);  psq[n] += __shfl_xor(psq[n], 2);
    psum[n] += __shfl_xor(psum[n], 16); psq[n] += __shfl_xor(psq[n], 16);
    psum[n] += __shfl_xor(psum[n], 32); psq[n] += __shfl_xor(psq[n], 32);
  }
  float* fs = (float*)RB;   // bias_s dead; PV touches RA/RC only
  if ((l & 3) == 0 && l < 16) {
    int g2 = l >> 2;
#pragma unroll
    for (int n = 0; n < 8; ++n) {
      int d = 4 * n + g2;
      if (d < D_) { fs[w * 32 + d] = psum[n]; fs[128 + w * 32 + d] = psq[n]; }
    }
  }
  __syncthreads();
  if (tid < D_) {
    float s = fs[tid] + fs[32 + tid] + fs[64 + tid] + fs[96 + tid];
    float s2 = fs[128 + tid] + fs[160 + tid] + fs[192 + tid] + fs[224 + tid];
    partial1[((size_t)b * 8 + h) * 62 + tid] = s;
    partial1[((size_t)b * 8 + h) * 62 + 31 + tid] = s2;
  }
  if (h == 7) {   // const column 992 (=1.0) and zero cols 993..1023 of p1T
    for (int u = tid; u < 400; u += 256) {
      int p = u >> 3, g3 = u & 7;
      ushort4 vz = make_ushort4(0, 0, 0, 0);
      if (g3 == 0) vz.x = 0x3F80;
      *(ushort4*)(p1T + ((size_t)b * 50 + p) * 1024 + 992 + g3 * 4) = vz;
    }
  }
}

// BN1 finalize: 248 blocks, thread = b; sums partial1 over b.
__global__ __launch_bounds__(256) void bnfin1_kernel(
    const float* __restrict__ partial1, const float* __restrict__ g,
    const float* __restrict__ be, float* __restrict__ a, float* __restrict__ bs) {
  const int c = blockIdx.x;
  const int h = c / D_, d = c - h * D_;
  const int tid = threadIdx.x;
  const float* pp = partial1 + ((size_t)tid * 8 + h) * 62;
  float s = pp[d], s2 = pp[31 + d];
#pragma unroll
  for (int off = 1; off <= 32; off <<= 1) {
    s += __shfl_xor(s, off);
    s2 += __shfl_xor(s2, off);
  }
  __shared__ float r1[4], r2[4];
  if ((tid & 63) == 0) { r1[tid >> 6] = s; r2[tid >> 6] = s2; }
  __syncthreads();
  if (tid == 0) {
    s = r1[0] + r1[1] + r1[2] + r1[3];
    s2 = r2[0] + r2[1] + r2[2] + r2[3];
    const float inv = 1.f / (float)(B_ * PT_);
    float m = s * inv;
    float var = s2 * inv - m * m;
    float ai = g[c] * rsqrtf(var + 1e-5f);
    a[c] = ai;
    bs[c] = be[c] - m * ai;
  }
}

// Parallel BN stats stage 1 (f32 input): grid (nch, 8)
__global__ __launch_bounds__(256) void bnstat_part_kernel(
    const float* __restrict__ t, float* __restrict__ part, int nch) {
  const int c = blockIdx.x, g = blockIdx.y;
  const int tid = threadIdx.x;
  const int bsl = tid >> 3, k = tid & 7;
  const int b = g * 32 + bsl;
  const float* base = t + ((size_t)b * nch + c) * PT_;
  float s = 0.f, s2 = 0.f;
  for (int j = k; j < 50; j += 8) {
    float4 v = *(const float4*)(base + j * 4);
    s += v.x + v.y + v.z + v.w;
    s2 += v.x * v.x + v.y * v.y + v.z * v.z + v.w * v.w;
  }
#pragma unroll
  for (int off = 1; off <= 32; off <<= 1) {
    s += __shfl_xor(s, off);
    s2 += __shfl_xor(s2, off);
  }
  __shared__ float r1[4], r2[4];
  if ((tid & 63) == 0) { r1[tid >> 6] = s; r2[tid >> 6] = s2; }
  __syncthreads();
  if (tid == 0) {
    s = r1[0] + r1[1] + r1[2] + r1[3];
    s2 = r2[0] + r2[1] + r2[2] + r2[3];
    part[((size_t)c * 8 + g) * 2] = s;
    part[((size_t)c * 8 + g) * 2 + 1] = s2;
  }
}

// Parallel BN stats stage 1 (bf16 input): grid (nch, 8)
__global__ __launch_bounds__(256) void bnstat_part_bf16_kernel(
    const unsigned short* __restrict__ t, float* __restrict__ part, int nch) {
  const int c = blockIdx.x, g = blockIdx.y;
  const int tid = threadIdx.x;
  const int bsl = tid >> 3, k = tid & 7;
  const int b = g * 32 + bsl;
  const unsigned short* base = t + ((size_t)b * nch + c) * PT_;
  float s = 0.f, s2 = 0.f;
  for (int j = k; j < 25; j += 8) {
    ushort4 v0 = *(const ushort4*)(base + j * 8);
    ushort4 v1 = *(const ushort4*)(base + j * 8 + 4);
    float e[8] = {bf2f(v0.x), bf2f(v0.y), bf2f(v0.z), bf2f(v0.w),
                  bf2f(v1.x), bf2f(v1.y), bf2f(v1.z), bf2f(v1.w)};
#pragma unroll
    for (int q = 0; q < 8; ++q) { s += e[q]; s2 += e[q] * e[q]; }
  }
#pragma unroll
  for (int off = 1; off <= 32; off <<= 1) {
    s += __shfl_xor(s, off);
    s2 += __shfl_xor(s2, off);
  }
  __shared__ float r1[4], r2[4];
  if ((tid & 63) == 0) { r1[tid >> 6] = s; r2[tid >> 6] = s2; }
  __syncthreads();
  if (tid == 0) {
    s = r1[0] + r1[1] + r1[2] + r1[3];
    s2 = r2[0] + r2[1] + r2[2] + r2[3];
    part[((size_t)c * 8 + g) * 2] = s;
    part[((size_t)c * 8 + g) * 2 + 1] = s2;
  }
}

// BN stats stage 2 (generic finalize)
__global__ __launch_bounds__(256) void bnfin_kernel(
    const float* __restrict__ part, const float* __restrict__ g,
    const float* __restrict__ be, float* __restrict__ a, float* __restrict__ bs, int nch) {
  int c = threadIdx.x;
  if (c < nch) {
    float s = 0.f, s2 = 0.f;
#pragma unroll
    for (int gg = 0; gg < 8; ++gg) {
      s += part[((size_t)c * 8 + gg) * 2];
      s2 += part[((size_t)c * 8 + gg) * 2 + 1];
    }
    const float inv = 1.f / (float)(B_ * PT_);
    float m = s * inv;
    float var = s2 * inv - m * m;
    float ai = g[c] * rsqrtf(var + 1e-5f);
    a[c] = ai;
    bs[c] = be[c] - m * ai;
  }
}

// K4b: build Wbig bf16 [64 n=(f,t)][1024 K=(c,t')+const] folding conv taps, a1, b1, bc
__global__ __launch_bounds__(256) void wcfe_kernel(
    const float* __restrict__ w1, const float* __restrict__ bc1,
    const float* __restrict__ w2, const float* __restrict__ bc2,
    const float* __restrict__ a1, const float* __restrict__ b1,
    unsigned short* __restrict__ Wbig) {
  const int n = blockIdx.x;
  const int f = n >> 2, t = n & 3;
  const int tid = threadIdx.x;
  __shared__ float red[256];
  float partial = 0.f;
  if (tid < C_) {
    int c = tid;
    float tv[4];
    float tsum = 0.f;
#pragma unroll
    for (int tp = 0; tp < 4; ++tp) {
      int dt = tp - t;
      float v = 0.f;
      if (f < 8) { if (dt >= -1 && dt <= 1) v = w1[(f * C_ + c) * 3 + dt + 1]; }
      else       { if (dt >= -2 && dt <= 2) v = w2[((f - 8) * C_ + c) * 5 + dt + 2]; }
      tv[tp] = v; tsum += v;
    }
    float ac = a1[c];
#pragma unroll
    for (int tp = 0; tp < 4; ++tp)
      Wbig[n * 1024 + c * 4 + tp] = f2bf(ac * tv[tp]);
    partial = b1[c] * tsum;
  } else {
#pragma unroll
    for (int tp = 0; tp < 4; ++tp) {
      int col = tid * 4 + tp;
      if (col > 992 && col < 1024) Wbig[n * 1024 + col] = 0;
    }
  }
  red[tid] = partial;
  __syncthreads();
  for (int s = 128; s > 0; s >>= 1) {
    if (tid < s) red[tid] += red[tid + s];
    __syncthreads();
  }
  if (tid == 0) {
    float bias = (f < 8) ? bc1[f] : bc2[f - 8];
    Wbig[n * 1024 + 992] = f2bf(bias + red[0]);
  }
}

// K4c: MFMA GEMM: y16[m=(b,p), n=(f,t)] = p1T[m] . Wbig[n].  M=12800, N=64, K=1024.
__global__ __launch_bounds__(256) void cfe12g_kernel(
    const unsigned short* __restrict__ p1T, const unsigned short* __restrict__ Wbig,
    float* __restrict__ y16) {
  const int tid = threadIdx.x;
  const int w = tid >> 6, l = tid & 63;
  const int lr = l & 15, lk = (l >> 4) * 8;
  const int m0 = blockIdx.x * 32;
  const f32x4 zf = {0.f, 0.f, 0.f, 0.f};
  f32x4 acc0 = zf, acc1 = zf;
  const unsigned short* wrow = Wbig + (size_t)(w * 16 + lr) * 1024;
#pragma unroll
  for (int ks = 0; ks < 32; ++ks) {
    int k0 = ks * 32 + lk;
    short8v bfr = *(const short8v*)(wrow + k0);
    short8v a0 = *(const short8v*)(p1T + (size_t)(m0 + lr) * 1024 + k0);
    short8v a1v = *(const short8v*)(p1T + (size_t)(m0 + 16 + lr) * 1024 + k0);
    acc0 = __builtin_amdgcn_mfma_f32_16x16x32_bf16(a0, bfr, acc0, 0, 0, 0);
    acc1 = __builtin_amdgcn_mfma_f32_16x16x32_bf16(a1v, bfr, acc1, 0, 0, 0);
  }
  const int n = w * 16 + lr, f = n >> 2, tt = n & 3;
#pragma unroll
  for (int mt = 0; mt < 2; ++mt) {
    f32x4 av = (mt == 0) ? acc0 : acc1;
#pragma unroll
    for (int r = 0; r < 4; ++r) {
      int m = m0 + mt * 16 + (l >> 4) * 4 + r;
      int b = m / 50, p = m - (m / 50) * 50;
      y16[((size_t)b * 16 + f) * PT_ + p * 4 + tt] = av[r];
    }
  }
}

// K6: ELU(BN_cfe(y16)) -> conv3 (16->248) + BN1-residual (p1T bf16) -> pre2 (bf16)
__global__ __launch_bounds__(256) void cfe3_kernel(
    const float* __restrict__ y16, const float* __restrict__ ac, const float* __restrict__ bcf,
    const float* __restrict__ w3, const float* __restrict__ bc3,
    const unsigned short* __restrict__ p1T, const float* __restrict__ a1, const float* __restrict__ b1,
    unsigned short* __restrict__ pre2) {
  const int b = blockIdx.x;
  const int tid = threadIdx.x;
  __shared__ float zs[16][PT_];
  __shared__ float w3s[C_][16];
  for (int i = tid; i < C_ * 16; i += 256) w3s[i >> 4][i & 15] = w3[i];
  for (int e = tid; e < 16 * PT_; e += 256) {
    int f = e / PT_, pt = e - f * PT_;
    float v = y16[((size_t)b * 16 + f) * PT_ + pt] * ac[f] + bcf[f];
    zs[f][pt] = (v > 0.f) ? v : (__expf(v) - 1.f);
  }
  __syncthreads();
  for (int e = tid; e < C_ * P_; e += 256) {
    int c = e / P_, p = e - (e / P_) * P_;
    float b3 = bc3[c];
    float4 o = make_float4(b3, b3, b3, b3);
#pragma unroll
    for (int f = 0; f < 16; ++f) {
      float wv = w3s[c][f];
      float4 z = *(const float4*)&zs[f][p * 4];
      o.x += wv * z.x; o.y += wv * z.y; o.z += wv * z.z; o.w += wv * z.w;
    }
    ushort4 xr = *(const ushort4*)(p1T + ((size_t)(b * 50 + p)) * 1024 + c * 4);
    float a1c = a1[c], b1c = b1[c];
    o.x += bf2f(xr.x) * a1c + b1c;
    o.y += bf2f(xr.y) * a1c + b1c;
    o.z += bf2f(xr.z) * a1c + b1c;
    o.w += bf2f(xr.w) * a1c + b1c;
    size_t idx = (((size_t)b * C_ + c) * P_ + p) * T_;
    ushort4 o4;
    o4.x = f2bf(o.x); o4.y = f2bf(o.y); o4.z = f2bf(o.z); o4.w = f2bf(o.w);
    *(ushort4*)(pre2 + idx) = o4;
  }
}

// K8: apply BN2 (bf16 pre2) -> out f32
__global__ __launch_bounds__(256) void bnapply_kernel(
    const unsigned short* __restrict__ pre2, const float* __restrict__ a,
    const float* __restrict__ bs, float* __restrict__ out) {
  int i = blockIdx.x * 256 + threadIdx.x;
  if (i < (B_ * C_ * PT_) / 4) {
    int row = (i * 4) / PT_;
    int c = row % C_;
    ushort4 v = *(const ushort4*)(pre2 + (size_t)i * 4);
    float ai = a[c], bi = bs[c];
    float4 o = make_float4(bf2f(v.x) * ai + bi, bf2f(v.y) * ai + bi,
                           bf2f(v.z) * ai + bi, bf2f(v.w) * ai + bi);
    *(float4*)(out + (size_t)i * 4) = o;
  }
}

extern "C" void kernel_launch(void* const* d_in, const int* in_sizes, int n_in,
                              void* d_out, int out_size, void* d_ws, size_t ws_size,
                              hipStream_t stream) {
  const float* x        = (const float*)d_in[0];
  const float* w_qkv    = (const float*)d_in[1];
  const float* b_qkv    = (const float*)d_in[2];
  const float* rel      = (const float*)d_in[3];
  const float* g1       = (const float*)d_in[4];
  const float* beta1    = (const float*)d_in[5];
  const float* w_c1     = (const float*)d_in[6];
  const float* bc1      = (const float*)d_in[7];
  const float* w_c2     = (const float*)d_in[8];
  const float* bc2      = (const float*)d_in[9];
  const float* g_cfe    = (const float*)d_in[10];
  const float* beta_cfe = (const float*)d_in[11];
  const float* w_c3     = (const float*)d_in[12];
  const float* bc3      = (const float*)d_in[13];
  const float* g2       = (const float*)d_in[14];
  const float* beta2    = (const float*)d_in[15];
  float* out = (float*)d_out;
  char* ws = (char*)d_ws;

  // ws layout (bytes):
  //   0          xT bf16 (27,262,976)   [dead after fused_qa]
  //   27262976   wbf bf16 (393,216)     [dead after fused_qa]
  //   27656192   p1T bf16 (26,214,400)  [fused_qa writes; cfe12g + cfe3 read]
  //   53870592   part2 f32 (15,872)
  //   53886464   partY f32 (1,024)
  //   76185600   pre2 bf16 (25,395,200)
  //   126976000  y16 f32 (3,276,800); partial1 f32 (507,904) aliases this region
  //   130252800  relp bf16 (28,672)
  //   130281472  Wbig bf16 (131,072)
  //   130412544  st f32
  unsigned short* xT    = (unsigned short*)(ws);
  unsigned short* wbf   = (unsigned short*)(ws + 27262976);
  unsigned short* p1T   = (unsigned short*)(ws + 27656192);
  float* part2          = (float*)(ws + 53870592);
  float* partY          = (float*)(ws + 53886464);
  unsigned short* pre2  = (unsigned short*)(ws + 76185600);
  float* y16            = (float*)(ws + 126976000);
  float* partial1       = (float*)(ws + 126976000);
  unsigned short* relp  = (unsigned short*)(ws + 130252800);
  unsigned short* Wbig  = (unsigned short*)(ws + 130281472);
  float* st             = (float*)(ws + 130412544);
  float* a1 = st, *b1 = st + 256, *acf = st + 512, *bcf = st + 544, *a2 = st + 576, *b2 = st + 832;

  relcvt_kernel<<<56, 256, 0, stream>>>(rel, relp);
  wcvt_kernel<<<192, 256, 0, stream>>>(w_qkv, wbf);
  xt_kernel<<<dim3(16, 256), 256, 0, stream>>>(x, xT);
  fused_qa_kernel<<<2048, 256, 0, stream>>>(xT, wbf, b_qkv, relp, p1T, partial1);
  bnfin1_kernel<<<248, 256, 0, stream>>>(partial1, g1, beta1, a1, b1);
  wcfe_kernel<<<64, 256, 0, stream>>>(w_c1, bc1, w_c2, bc2, a1, b1, Wbig);
  cfe12g_kernel<<<400, 256, 0, stream>>>(p1T, Wbig, y16);
  bnstat_part_kernel<<<dim3(16, 8), 256, 0, stream>>>(y16, partY, 16);
  bnfin_kernel<<<1, 256, 0, stream>>>(partY, g_cfe, beta_cfe, acf, bcf, 16);
  cfe3_kernel<<<256, 256, 0, stream>>>(y16, acf, bcf, w_c3, bc3, p1T, a1, b1, pre2);
  bnstat_part_bf16_kernel<<<dim3(248, 8), 256, 0, stream>>>(pre2, part2, 248);
  bnfin_kernel<<<1, 256, 0, stream>>>(part2, g2, beta2, a2, b2, 248);
  bnapply_kernel<<<12400, 256, 0, stream>>>(pre2, a2, b2, out);
}